// Round 6
// baseline (537.599 us; speedup 1.0000x reference)
//
#include <hip/hip_runtime.h>
#include <hip/hip_bf16.h>
#include <stdint.h>

#define B_ 16
#define N_ 64
#define S_ 4096
#define C_ 384
#define H_ 6
#define DH_ 64
#define SCALE_ 0.125f
#define TAU_ 2e-4f
#define LISTCAP 262144

typedef __attribute__((ext_vector_type(8))) short bf16x8;
typedef __attribute__((ext_vector_type(4))) float f32x4;

static __device__ __forceinline__ unsigned short f2bf(float x) {
    union { float f; unsigned u; } v; v.f = x;
    unsigned r = v.u + 0x7FFFu + ((v.u >> 16) & 1u);
    return (unsigned short)(r >> 16);
}
static __device__ __forceinline__ float bf2f(unsigned short b) {
    union { unsigned u; float f; } v; v.u = ((unsigned)b) << 16; return v.f;
}
static __device__ __forceinline__ float bfu_lo(unsigned u) {
    union { unsigned u; float f; } v; v.u = u << 16; return v.f;
}
static __device__ __forceinline__ float bfu_hi(unsigned u) {
    union { unsigned u; float f; } v; v.u = u & 0xFFFF0000u; return v.f;
}

// async global->LDS, 16B/lane; LDS dest = wave-uniform base + lane*16
static __device__ __forceinline__ void gl_lds16(const void* g, void* l) {
    __builtin_amdgcn_global_load_lds(
        (const __attribute__((address_space(1))) unsigned int*)g,
        (__attribute__((address_space(3))) unsigned int*)l, 16, 0, 0);
}

// ---------------------------------------------------------------------------
// K0+K1 fused: prep (key -> khi/klo) + q-proj/fold-Wk. (r4 state, known-good)
// ---------------------------------------------------------------------------
#define PREP_BLOCKS 8192   // 8192 * 384 threads * 8 elems = 16*4096*384
#define QK_BLOCKS   (8 * H_ * B_)   // N_/8 x H x B = 768

__global__ __launch_bounds__(384) void prepqk_kernel(const float* __restrict__ key,
                                                     unsigned short* __restrict__ khi,
                                                     unsigned short* __restrict__ klo,
                                                     const float* __restrict__ query,
                                                     const float* __restrict__ Wq,
                                                     const float* __restrict__ Wk,
                                                     float* __restrict__ qk,
                                                     unsigned short* __restrict__ qkhi,
                                                     unsigned short* __restrict__ qklo) {
    if (blockIdx.x < PREP_BLOCKS) {
        size_t gid = (size_t)blockIdx.x * 384 + threadIdx.x;
        size_t base = gid * 8;
        float4 x0 = *(const float4*)(key + base);
        float4 x1 = *(const float4*)(key + base + 4);
        float xs[8] = { x0.x, x0.y, x0.z, x0.w, x1.x, x1.y, x1.z, x1.w };
        unsigned short hi[8], lo[8];
#pragma unroll
        for (int i = 0; i < 8; ++i) {
            hi[i] = f2bf(xs[i]);
            lo[i] = f2bf(xs[i] - bf2f(hi[i]));
        }
        *(bf16x8*)(khi + base) = *(bf16x8*)hi;
        *(bf16x8*)(klo + base) = *(bf16x8*)lo;
        return;
    }
    // ---- qk part ----
    __shared__ float qstage[8][C_];
    __shared__ float qv[8][DH_];
    int e = blockIdx.x - PREP_BLOCKS;           // 0..767
    int ng = e & 7;                             // 8 row-tiles
    int h = (e >> 3) % H_;
    int b = e / (8 * H_);
    int t = threadIdx.x;
    int n0 = ng * 8;
#pragma unroll
    for (int i = 0; i < 8; ++i)
        qstage[i][t] = query[((size_t)(b * N_ + n0 + i)) * C_ + t];
    __syncthreads();
    if (t < 256) {
        int i0 = t >> 6, d = t & 63;
        const float4* wq = (const float4*)(Wq + (size_t)(h * DH_ + d) * C_);
        float accA = 0.f, accB = 0.f;
#pragma unroll 4
        for (int c4 = 0; c4 < C_ / 4; ++c4) {
            float4 w = wq[c4];
            float4 qa = *(const float4*)&qstage[i0][c4 * 4];
            float4 qb = *(const float4*)&qstage[i0 + 4][c4 * 4];
            accA += qa.x * w.x + qa.y * w.y + qa.z * w.z + qa.w * w.w;
            accB += qb.x * w.x + qb.y * w.y + qb.z * w.z + qb.w * w.w;
        }
        qv[i0][d] = accA * SCALE_;
        qv[i0 + 4][d] = accB * SCALE_;
    }
    __syncthreads();
    {
        float a[8];
#pragma unroll
        for (int i = 0; i < 8; ++i) a[i] = 0.f;
        const float* wk = Wk + (size_t)h * DH_ * C_ + t;
#pragma unroll 4
        for (int d = 0; d < DH_; ++d) {
            float w = wk[(size_t)d * C_];
#pragma unroll
            for (int i = 0; i < 8; ++i) a[i] += qv[i][d] * w;
        }
#pragma unroll
        for (int i = 0; i < 8; ++i) {
            size_t o = ((size_t)(b * H_ + h) * N_ + n0 + i) * C_ + t;
            float v = a[i];
            qk[o] = v;
            unsigned short hi = f2bf(v);
            qkhi[o] = hi;
            qklo[o] = f2bf(v - bf2f(hi));
        }
    }
}

// ---------------------------------------------------------------------------
// K2: logits via 3-pass bf16 MFMA + argmax. 64n x 128 tokens per block.
// (round-3 state, known-good)
// ---------------------------------------------------------------------------
__global__ __launch_bounds__(256) void attn_kernel(const unsigned short* __restrict__ qkhi,
                                                   const unsigned short* __restrict__ qklo,
                                                   const unsigned short* __restrict__ khi,
                                                   const unsigned short* __restrict__ klo,
                                                   unsigned int* __restrict__ idx,
                                                   unsigned int* __restrict__ flag_cnt,
                                                   unsigned int* __restrict__ flag_list) {
    __shared__ __align__(16) unsigned short sAhi[64 * 32];
    __shared__ __align__(16) unsigned short sAlo[64 * 32];
    __shared__ __align__(16) unsigned short sBhi[128 * 32];
    __shared__ __align__(16) unsigned short sBlo[128 * 32];
    int tid = threadIdx.x;
    int w = tid >> 6, l = tid & 63;          // w in 0..3
    int wm = w >> 1, wn = w & 1;             // 2 x 2 wave grid (32q x 64tok each)
    int q4 = l >> 4, lm = l & 15;
    int s0 = blockIdx.x * 128;
    int h = blockIdx.y, b = blockIdx.z;
    size_t kbK = ((size_t)b * S_ + s0) * C_;
    size_t kbA = (size_t)(b * H_ + h) * N_ * C_;
    int trow16 = l >> 2;
    int tquart = ((l & 3) ^ ((l >> 3) & 3)) * 8;
    int sw = (q4 ^ ((lm >> 1) & 3)) * 8;

    f32x4 acc[2][4];
#pragma unroll
    for (int tm = 0; tm < 2; ++tm)
#pragma unroll
        for (int nt = 0; nt < 4; ++nt) acc[tm][nt] = (f32x4)0.f;

    for (int kc = 0; kc < C_; kc += 32) {
        __syncthreads();
#pragma unroll
        for (int i = 0; i < 6; ++i) {
            int gid = w * 6 + i;
            if (gid < 8) {
                gl_lds16(khi + kbK + (size_t)(gid * 16 + trow16) * C_ + kc + tquart,
                         (char*)sBhi + gid * 1024);
            } else if (gid < 16) {
                int g2 = gid - 8;
                gl_lds16(klo + kbK + (size_t)(g2 * 16 + trow16) * C_ + kc + tquart,
                         (char*)sBlo + g2 * 1024);
            } else if (gid < 20) {
                int g2 = gid - 16;
                gl_lds16(qkhi + kbA + (size_t)(g2 * 16 + trow16) * C_ + kc + tquart,
                         (char*)sAhi + g2 * 1024);
            } else {
                int g2 = gid - 20;
                gl_lds16(qklo + kbA + (size_t)(g2 * 16 + trow16) * C_ + kc + tquart,
                         (char*)sAlo + g2 * 1024);
            }
        }
        __syncthreads();
        bf16x8 ah[2], al[2];
#pragma unroll
        for (int tm = 0; tm < 2; ++tm) {
            int ar = (wm * 32 + tm * 16 + lm) * 32 + sw;
            ah[tm] = *(const bf16x8*)&sAhi[ar];
            al[tm] = *(const bf16x8*)&sAlo[ar];
        }
#pragma unroll
        for (int nt = 0; nt < 4; ++nt) {
            int nr = ((wn * 4 + nt) * 16 + lm) * 32 + sw;
            bf16x8 bh = *(const bf16x8*)&sBhi[nr];
            bf16x8 bl = *(const bf16x8*)&sBlo[nr];
#pragma unroll
            for (int tm = 0; tm < 2; ++tm) {
                acc[tm][nt] = __builtin_amdgcn_mfma_f32_16x16x32_bf16(ah[tm], bh, acc[tm][nt], 0, 0, 0);
                acc[tm][nt] = __builtin_amdgcn_mfma_f32_16x16x32_bf16(ah[tm], bl, acc[tm][nt], 0, 0, 0);
                acc[tm][nt] = __builtin_amdgcn_mfma_f32_16x16x32_bf16(al[tm], bh, acc[tm][nt], 0, 0, 0);
            }
        }
    }
    __syncthreads();

    float* rm1 = (float*)sBhi;   // scratch aliases sBhi; safe after final barrier
    float* rm2 = rm1 + 256;      // 2 wm-halves x 128 tokens
    int* ri1 = (int*)(rm2 + 256);
    int* ri2 = ri1 + 256;

#pragma unroll
    for (int nt = 0; nt < 4; ++nt) {
        float m1 = -3.4e38f, m2 = -3.4e38f; int i1 = 0, i2 = 0;
#pragma unroll
        for (int tm = 0; tm < 2; ++tm)
#pragma unroll
            for (int r = 0; r < 4; ++r) {
                float v = acc[tm][nt][r];
                int row = wm * 32 + tm * 16 + q4 * 4 + r;
                if (v > m1) { m2 = m1; i2 = i1; m1 = v; i1 = row; }
                else if (v > m2) { m2 = v; i2 = row; }
            }
#pragma unroll
        for (int off = 16; off < 64; off <<= 1) {
            float om1 = __shfl_xor(m1, off), om2 = __shfl_xor(m2, off);
            int oi1 = __shfl_xor(i1, off), oi2 = __shfl_xor(i2, off);
            bool take = (om1 > m1) || (om1 == m1 && oi1 < i1);
            float w1 = take ? om1 : m1; int wi1 = take ? oi1 : i1;
            float l1 = take ? m1 : om1; int li1 = take ? i1 : oi1;
            float s2 = m2; int si2 = i2;
            if (om2 > s2) { s2 = om2; si2 = oi2; }
            if (l1 > s2) { s2 = l1; si2 = li1; }
            m1 = w1; i1 = wi1; m2 = s2; i2 = si2;
        }
        if (q4 == 0) {
            int cw = (wn * 4 + nt) * 16 + lm;      // token col 0..127
            rm1[wm * 128 + cw] = m1; rm2[wm * 128 + cw] = m2;
            ri1[wm * 128 + cw] = i1; ri2[wm * 128 + cw] = i2;
        }
    }
    __syncthreads();
    if (tid < 128) {
        float a1 = rm1[tid], a2 = rm2[tid];
        int ai1 = ri1[tid], ai2 = ri2[tid];
        float b1 = rm1[128 + tid], b2 = rm2[128 + tid];
        int bi1 = ri1[128 + tid], bi2 = ri2[128 + tid];
        float w1, s2; int wi1, wi2;
        if (b1 > a1) { w1 = b1; wi1 = bi1; s2 = a1; wi2 = ai1; if (b2 > s2) { s2 = b2; wi2 = bi2; } }
        else         { w1 = a1; wi1 = ai1; s2 = a2; wi2 = ai2; if (b1 > s2) { s2 = b1; wi2 = bi1; } }
        idx[(size_t)(b * H_ + h) * S_ + s0 + tid] = (unsigned)wi1;
        if (w1 - s2 < TAU_) {
            unsigned p = atomicAdd(flag_cnt, 1u);
            if (p < LISTCAP) {
                unsigned tok = (unsigned)((b * H_ + h) * S_ + s0 + tid);
                flag_list[p] = tok | ((unsigned)wi1 << 19) | ((unsigned)wi2 << 25);
            }
        }
    }
}

// ---------------------------------------------------------------------------
// K3: fixup — exact fp32 recompute of two candidate rows for near-ties
// ---------------------------------------------------------------------------
__global__ __launch_bounds__(256) void fixup_kernel(const float* __restrict__ qk,
                                                    const float* __restrict__ key,
                                                    const unsigned int* __restrict__ flag_list,
                                                    const unsigned int* __restrict__ flag_cnt,
                                                    unsigned int* __restrict__ idx) {
    int w = threadIdx.x >> 6, l = threadIdx.x & 63;
    unsigned total = flag_cnt[0];
    if (total > LISTCAP) total = LISTCAP;
    for (unsigned t = blockIdx.x * 4 + w; t < total; t += gridDim.x * 4) {
        unsigned e = flag_list[t];
        unsigned tok = e & 0x7FFFFu;
        int i1 = (int)((e >> 19) & 63u), i2 = (int)((e >> 25) & 63u);
        unsigned bh = tok >> 12;
        unsigned s = tok & 4095u;
        unsigned bb = bh / H_;
        int l32 = l & 31;
        const float* qrow = qk + ((size_t)bh * N_ + (l < 32 ? i1 : i2)) * C_ + l32 * 12;
        const float* krow = key + ((size_t)bb * S_ + s) * C_ + l32 * 12;
        float sum = 0.f;
#pragma unroll
        for (int c = 0; c < 12; ++c) sum += qrow[c] * krow[c];
#pragma unroll
        for (int off = 1; off < 32; off <<= 1) sum += __shfl_xor(sum, off);
        float d1 = __shfl(sum, 0);
        float d2 = __shfl(sum, 32);
        int win = (d2 > d1 || (d2 == d1 && i2 < i1)) ? i2 : i1;
        if (l == 0) idx[(size_t)bh * S_ + s] = (unsigned)win;
    }
}

// ---------------------------------------------------------------------------
// K4: hist_build — per (b,h): histogram -> scan -> counting-sort placement
// ---------------------------------------------------------------------------
__global__ __launch_bounds__(256) void hist_build_kernel(const unsigned int* __restrict__ idx,
                                                         unsigned int* __restrict__ offs,
                                                         unsigned int* __restrict__ order) {
    __shared__ unsigned int cnts[N_];
    __shared__ unsigned int pos[N_];
    int tid = threadIdx.x;
    int bh = blockIdx.x;
    if (tid < N_) cnts[tid] = 0u;
    __syncthreads();
    const unsigned int* idxp = idx + (size_t)bh * S_;
    for (int s = tid; s < S_; s += 256) atomicAdd(&cnts[idxp[s]], 1u);
    __syncthreads();
    if (tid < N_) {
        unsigned v = cnts[tid];
        unsigned x = v;
#pragma unroll
        for (int off = 1; off < 64; off <<= 1) {
            unsigned y = __shfl_up(x, off);
            if (tid >= off) x += y;
        }
        unsigned excl = x - v;
        pos[tid] = excl;
        offs[(size_t)bh * 65 + tid] = excl;
        if (tid == 63) offs[(size_t)bh * 65 + 64] = x;   // == S_
    }
    __syncthreads();
    unsigned int* op = order + (size_t)bh * S_;
    for (int s = tid; s < S_; s += 256) {
        unsigned g = idxp[s];
        unsigned p = atomicAdd(&pos[g], 1u);
        op[p] = (unsigned)s;
    }
}

// ---------------------------------------------------------------------------
// K5a: agg — SKEW-PROOF token-chunk decomposition (r5 post-mortem: per-group
// waves serialized on the fattest argmax bucket -> 131us at 13% VALU).
// One wave per 64-token chunk of the SORTED order list (6144 waves, always
// exactly 64 iters — perfectly balanced). Group id is non-decreasing along
// the chunk; partial row (lane owns cols l*6..l*6+5) is flushed to acc[]
// via fp32 atomicAdd only at group boundaries (~128 flushes/bh). Note:
// within-group order is ALREADY non-deterministic (hist's atomic placement),
// so atomic accumulation adds no new correctness class.
// ---------------------------------------------------------------------------
__global__ __launch_bounds__(256) void agg_kernel(const unsigned short* __restrict__ khi,
                                                  const unsigned int* __restrict__ order,
                                                  const unsigned int* __restrict__ idx,
                                                  float* __restrict__ acc) {
    int tid = threadIdx.x;
    int w = tid >> 6, l = tid & 63;
    int h = blockIdx.y, b = blockIdx.z;
    int bh = b * H_ + h;
    int chunk = blockIdx.x * 4 + w;          // 0..63
    const unsigned int* op = order + (size_t)bh * S_ + chunk * 64;
    unsigned sv = op[l];                     // my token id
    unsigned gv = idx[(size_t)bh * S_ + sv]; // its group
    const unsigned int* kbase = (const unsigned int*)(khi + (size_t)b * S_ * C_);
    float* accb = acc + (size_t)bh * N_ * C_;
    float a0 = 0.f, a1 = 0.f, a2 = 0.f, a3 = 0.f, a4 = 0.f, a5 = 0.f;
    int cur_g = __shfl((int)gv, 0);
#pragma unroll 4
    for (int i = 0; i < 64; ++i) {
        int s = __shfl((int)sv, i);
        int g = __shfl((int)gv, i);
        if (g != cur_g) {                    // wave-uniform, rare
            float* ap = accb + (size_t)cur_g * C_ + l * 6;
            atomicAdd(ap + 0, a0); atomicAdd(ap + 1, a1); atomicAdd(ap + 2, a2);
            atomicAdd(ap + 3, a3); atomicAdd(ap + 4, a4); atomicAdd(ap + 5, a5);
            a0 = a1 = a2 = a3 = a4 = a5 = 0.f;
            cur_g = g;
        }
        const unsigned int* kp = kbase + (size_t)s * (C_ / 2) + l * 3;
        unsigned u0 = kp[0], u1 = kp[1], u2 = kp[2];
        a0 += bfu_lo(u0); a1 += bfu_hi(u0);
        a2 += bfu_lo(u1); a3 += bfu_hi(u1);
        a4 += bfu_lo(u2); a5 += bfu_hi(u2);
    }
    float* ap = accb + (size_t)cur_g * C_ + l * 6;
    atomicAdd(ap + 0, a0); atomicAdd(ap + 1, a1); atomicAdd(ap + 2, a2);
    atomicAdd(ap + 3, a3); atomicAdd(ap + 4, a4); atomicAdd(ap + 5, a5);
}

// ---------------------------------------------------------------------------
// K5b: gv2 — one wave per (bh, group): stage acc row in LDS, scale by
// 1/(cnt+1) once at the end, dot with Wv rows (old gv structure).
// ---------------------------------------------------------------------------
__global__ __launch_bounds__(256) void gv2_kernel(const float* __restrict__ acc,
                                                  const unsigned int* __restrict__ offs,
                                                  const float* __restrict__ Wv,
                                                  float* __restrict__ gvn) {
    __shared__ float rows[4][C_];
    int tid = threadIdx.x;
    int w = tid >> 6, l = tid & 63;
    int h = blockIdx.y, b = blockIdx.z;
    int bh = b * H_ + h;
    int g = blockIdx.x * 4 + w;
    unsigned beg = offs[(size_t)bh * 65 + g];
    unsigned end = offs[(size_t)bh * 65 + g + 1];
    float inv = 1.f / ((float)(end - beg) + 1.f);
    const float* arow = acc + ((size_t)bh * N_ + g) * C_;
    for (int i = l; i < C_ / 4; i += 64)
        *(float4*)&rows[w][i * 4] = ((const float4*)arow)[i];
    __syncthreads();
    const float* wrow = Wv + (size_t)(h * DH_ + l) * C_;
    float s = 0.f;
#pragma unroll 8
    for (int c4 = 0; c4 < C_ / 4; ++c4) {
        float4 a = *(const float4*)&rows[w][c4 * 4];
        float4 wv = *(const float4*)&wrow[c4 * 4];
        s += a.x * wv.x + a.y * wv.y + a.z * wv.z + a.w * wv.w;
    }
    gvn[((size_t)bh * N_ + g) * DH_ + l] = s * inv;
}

// ---------------------------------------------------------------------------
// K7: out — 4 tokens per block (r4 state, known-good)
// ---------------------------------------------------------------------------
__global__ __launch_bounds__(384) void out_kernel(const float* __restrict__ gvn,
                                                  const float* __restrict__ Wp,
                                                  const float* __restrict__ bp,
                                                  float* __restrict__ out) {
    __shared__ float vals[4][C_];
    int blk = blockIdx.x;                 // 0..255
    int b = blk >> 4, n0 = (blk & 15) * 4;
    int t = threadIdx.x;
    int h = t >> 6, d = t & 63;
#pragma unroll
    for (int j = 0; j < 4; ++j)
        vals[j][t] = gvn[((size_t)(b * H_ + h) * N_ + n0 + j) * DH_ + d];
    __syncthreads();
    const float4* w4 = (const float4*)(Wp + (size_t)t * C_);
    float s0 = bp[t], s1 = s0, s2 = s0, s3 = s0;
    const float4* v0 = (const float4*)vals[0];
    const float4* v1 = (const float4*)vals[1];
    const float4* v2 = (const float4*)vals[2];
    const float4* v3 = (const float4*)vals[3];
#pragma unroll 4
    for (int i = 0; i < C_ / 4; ++i) {
        float4 w = w4[i];
        float4 a0 = v0[i]; s0 += a0.x * w.x + a0.y * w.y + a0.z * w.z + a0.w * w.w;
        float4 a1 = v1[i]; s1 += a1.x * w.x + a1.y * w.y + a1.z * w.z + a1.w * w.w;
        float4 a2 = v2[i]; s2 += a2.x * w.x + a2.y * w.y + a2.z * w.z + a2.w * w.w;
        float4 a3 = v3[i]; s3 += a3.x * w.x + a3.y * w.y + a3.z * w.z + a3.w * w.w;
    }
    size_t ob = ((size_t)b * N_ + n0) * C_ + t;
    out[ob] = s0;
    out[ob + C_] = s1;
    out[ob + 2 * C_] = s2;
    out[ob + 3 * C_] = s3;
}

// ---------------------------------------------------------------------------
extern "C" void kernel_launch(void* const* d_in, const int* in_sizes, int n_in,
                              void* d_out, int out_size, void* d_ws, size_t ws_size,
                              hipStream_t stream) {
    (void)in_sizes; (void)n_in; (void)out_size; (void)ws_size;
    const float* query = (const float*)d_in[0];
    const float* key   = (const float*)d_in[1];
    const float* Wq    = (const float*)d_in[2];
    const float* Wk    = (const float*)d_in[3];
    const float* Wv    = (const float*)d_in[4];
    const float* Wp    = (const float*)d_in[5];
    const float* bp    = (const float*)d_in[6];
    float* out = (float*)d_out;

    char* ws = (char*)d_ws;
    size_t off = 0;
    unsigned short* khi  = (unsigned short*)(ws + off); off += (size_t)B_ * S_ * C_ * 2;
    unsigned short* klo  = (unsigned short*)(ws + off); off += (size_t)B_ * S_ * C_ * 2;
    float* qk            = (float*)(ws + off);          off += (size_t)B_ * H_ * N_ * C_ * 4;
    unsigned short* qkhi = (unsigned short*)(ws + off); off += (size_t)B_ * H_ * N_ * C_ * 2;
    unsigned short* qklo = (unsigned short*)(ws + off); off += (size_t)B_ * H_ * N_ * C_ * 2;
    unsigned int* idx    = (unsigned int*)(ws + off);   off += (size_t)B_ * H_ * S_ * 4;
    unsigned int* order  = (unsigned int*)(ws + off);   off += (size_t)B_ * H_ * S_ * 4;
    unsigned int* offs   = (unsigned int*)(ws + off);   off += (size_t)B_ * H_ * 65 * 4;
    float* acc           = (float*)(ws + off);          off += (size_t)B_ * H_ * N_ * C_ * 4;
    float* gvn           = (float*)(ws + off);          off += (size_t)B_ * H_ * N_ * DH_ * 4;
    unsigned int* fcnt   = (unsigned int*)(ws + off);   off += 256;
    unsigned int* flist  = (unsigned int*)(ws + off);   off += (size_t)LISTCAP * 4;

    hipMemsetAsync(fcnt, 0, 256, stream);
    hipMemsetAsync(acc, 0, (size_t)B_ * H_ * N_ * C_ * 4, stream);

    prepqk_kernel<<<PREP_BLOCKS + QK_BLOCKS, 384, 0, stream>>>(key, khi, klo,
                                                               query, Wq, Wk, qk, qkhi, qklo);
    attn_kernel<<<dim3(S_ / 128, H_, B_), 256, 0, stream>>>(qkhi, qklo, khi, klo, idx, fcnt, flist);
    fixup_kernel<<<256, 256, 0, stream>>>(qk, key, flist, fcnt, idx);
    hist_build_kernel<<<B_ * H_, 256, 0, stream>>>(idx, offs, order);
    agg_kernel<<<dim3(16, H_, B_), 256, 0, stream>>>(khi, order, idx, acc);
    gv2_kernel<<<dim3(16, H_, B_), 256, 0, stream>>>(acc, offs, Wv, gvn);
    out_kernel<<<B_ * N_ / 4, 384, 0, stream>>>(gvn, Wp, bp, out);
}

// Round 7
// 482.975 us; speedup vs baseline: 1.1131x; 1.1131x over previous
//
#include <hip/hip_runtime.h>
#include <hip/hip_bf16.h>
#include <stdint.h>

#define B_ 16
#define N_ 64
#define S_ 4096
#define C_ 384
#define H_ 6
#define DH_ 64
#define SCALE_ 0.125f
#define TAU_ 2e-4f
#define LISTCAP 262144

typedef __attribute__((ext_vector_type(8))) short bf16x8;
typedef __attribute__((ext_vector_type(4))) float f32x4;

static __device__ __forceinline__ unsigned short f2bf(float x) {
    union { float f; unsigned u; } v; v.f = x;
    unsigned r = v.u + 0x7FFFu + ((v.u >> 16) & 1u);
    return (unsigned short)(r >> 16);
}
static __device__ __forceinline__ float bf2f(unsigned short b) {
    union { unsigned u; float f; } v; v.u = ((unsigned)b) << 16; return v.f;
}
static __device__ __forceinline__ float bfu_lo(unsigned u) {
    union { unsigned u; float f; } v; v.u = u << 16; return v.f;
}
static __device__ __forceinline__ float bfu_hi(unsigned u) {
    union { unsigned u; float f; } v; v.u = u & 0xFFFF0000u; return v.f;
}

// async global->LDS, 16B/lane; LDS dest = wave-uniform base + lane*16
static __device__ __forceinline__ void gl_lds16(const void* g, void* l) {
    __builtin_amdgcn_global_load_lds(
        (const __attribute__((address_space(1))) unsigned int*)g,
        (__attribute__((address_space(3))) unsigned int*)l, 16, 0, 0);
}

// ---------------------------------------------------------------------------
// K0+K1 fused: prep (key -> khi/klo) + q-proj/fold-Wk.
// ROUND-THIS: phase-2 stores were the invariant ~90us (9216 scalar 2B/4B
// store instrs/block, transaction-limited — duration invariant to occupancy
// r3/r4/r6). Fix: compute a[8] bit-identically, round-trip through LDS
// (reusing qstage, dead after phase 1), then store row-major vectorized:
// 2x float4 + 2x bf16x8 per thread = 1536 store instrs/block (6x fewer,
// all >=16B). qk/qkhi/qklo bytes identical.
// ---------------------------------------------------------------------------
#define PREP_BLOCKS 8192   // 8192 * 384 threads * 8 elems = 16*4096*384
#define QK_BLOCKS   (8 * H_ * B_)   // N_/8 x H x B = 768

__global__ __launch_bounds__(384) void prepqk_kernel(const float* __restrict__ key,
                                                     unsigned short* __restrict__ khi,
                                                     unsigned short* __restrict__ klo,
                                                     const float* __restrict__ query,
                                                     const float* __restrict__ Wq,
                                                     const float* __restrict__ Wk,
                                                     float* __restrict__ qk,
                                                     unsigned short* __restrict__ qkhi,
                                                     unsigned short* __restrict__ qklo) {
    if (blockIdx.x < PREP_BLOCKS) {
        size_t gid = (size_t)blockIdx.x * 384 + threadIdx.x;
        size_t base = gid * 8;
        float4 x0 = *(const float4*)(key + base);
        float4 x1 = *(const float4*)(key + base + 4);
        float xs[8] = { x0.x, x0.y, x0.z, x0.w, x1.x, x1.y, x1.z, x1.w };
        unsigned short hi[8], lo[8];
#pragma unroll
        for (int i = 0; i < 8; ++i) {
            hi[i] = f2bf(xs[i]);
            lo[i] = f2bf(xs[i] - bf2f(hi[i]));
        }
        *(bf16x8*)(khi + base) = *(bf16x8*)hi;
        *(bf16x8*)(klo + base) = *(bf16x8*)lo;
        return;
    }
    // ---- qk part ----
    __shared__ float qstage[8][C_];   // phase 1: staged query rows; phase 2: qout transpose buffer
    __shared__ float qv[8][DH_];
    int e = blockIdx.x - PREP_BLOCKS;           // 0..767
    int ng = e & 7;                             // 8 row-tiles
    int h = (e >> 3) % H_;
    int b = e / (8 * H_);
    int t = threadIdx.x;
    int n0 = ng * 8;
#pragma unroll
    for (int i = 0; i < 8; ++i)
        qstage[i][t] = query[((size_t)(b * N_ + n0 + i)) * C_ + t];
    __syncthreads();
    if (t < 256) {
        int i0 = t >> 6, d = t & 63;
        const float4* wq = (const float4*)(Wq + (size_t)(h * DH_ + d) * C_);
        float accA = 0.f, accB = 0.f;
#pragma unroll 4
        for (int c4 = 0; c4 < C_ / 4; ++c4) {
            float4 w = wq[c4];
            float4 qa = *(const float4*)&qstage[i0][c4 * 4];
            float4 qb = *(const float4*)&qstage[i0 + 4][c4 * 4];
            accA += qa.x * w.x + qa.y * w.y + qa.z * w.z + qa.w * w.w;
            accB += qb.x * w.x + qb.y * w.y + qb.z * w.z + qb.w * w.w;
        }
        qv[i0][d] = accA * SCALE_;
        qv[i0 + 4][d] = accB * SCALE_;
    }
    __syncthreads();
    // phase 2a: qk[n,t] = sum_d qv[n][d] * Wk[h*64+d][t] — per-element dot
    // order identical to all prior rounds (sequential d).
    float a[8];
#pragma unroll
    for (int i = 0; i < 8; ++i) a[i] = 0.f;
    {
        const float* wk = Wk + (size_t)h * DH_ * C_ + t;
#pragma unroll 4
        for (int d = 0; d < DH_; ++d) {
            float w = wk[(size_t)d * C_];
#pragma unroll
            for (int i = 0; i < 8; ++i) a[i] += qv[i][d] * w;
        }
    }
    // phase 2b: LDS transpose (qstage dead since phase 1) -> vector stores
#pragma unroll
    for (int i = 0; i < 8; ++i) qstage[i][t] = a[i];
    __syncthreads();
    {
        int r = t / 48, c0 = (t % 48) * 8;
        float v[8];
#pragma unroll
        for (int j = 0; j < 8; ++j) v[j] = qstage[r][c0 + j];
        unsigned short hi[8], lo[8];
#pragma unroll
        for (int j = 0; j < 8; ++j) {
            hi[j] = f2bf(v[j]);
            lo[j] = f2bf(v[j] - bf2f(hi[j]));
        }
        size_t o = ((size_t)(b * H_ + h) * N_ + n0 + r) * C_ + c0;
        float4 f0 = { v[0], v[1], v[2], v[3] };
        float4 f1 = { v[4], v[5], v[6], v[7] };
        *(float4*)(qk + o) = f0;
        *(float4*)(qk + o + 4) = f1;
        *(bf16x8*)(qkhi + o) = *(bf16x8*)hi;
        *(bf16x8*)(qklo + o) = *(bf16x8*)lo;
    }
}

// ---------------------------------------------------------------------------
// K2: logits via 3-pass bf16 MFMA + argmax. 64n x 128 tokens per block.
// (round-3 state, known-good)
// ---------------------------------------------------------------------------
__global__ __launch_bounds__(256) void attn_kernel(const unsigned short* __restrict__ qkhi,
                                                   const unsigned short* __restrict__ qklo,
                                                   const unsigned short* __restrict__ khi,
                                                   const unsigned short* __restrict__ klo,
                                                   unsigned int* __restrict__ idx,
                                                   unsigned int* __restrict__ flag_cnt,
                                                   unsigned int* __restrict__ flag_list) {
    __shared__ __align__(16) unsigned short sAhi[64 * 32];
    __shared__ __align__(16) unsigned short sAlo[64 * 32];
    __shared__ __align__(16) unsigned short sBhi[128 * 32];
    __shared__ __align__(16) unsigned short sBlo[128 * 32];
    int tid = threadIdx.x;
    int w = tid >> 6, l = tid & 63;          // w in 0..3
    int wm = w >> 1, wn = w & 1;             // 2 x 2 wave grid (32q x 64tok each)
    int q4 = l >> 4, lm = l & 15;
    int s0 = blockIdx.x * 128;
    int h = blockIdx.y, b = blockIdx.z;
    size_t kbK = ((size_t)b * S_ + s0) * C_;
    size_t kbA = (size_t)(b * H_ + h) * N_ * C_;
    int trow16 = l >> 2;
    int tquart = ((l & 3) ^ ((l >> 3) & 3)) * 8;
    int sw = (q4 ^ ((lm >> 1) & 3)) * 8;

    f32x4 acc[2][4];
#pragma unroll
    for (int tm = 0; tm < 2; ++tm)
#pragma unroll
        for (int nt = 0; nt < 4; ++nt) acc[tm][nt] = (f32x4)0.f;

    for (int kc = 0; kc < C_; kc += 32) {
        __syncthreads();
#pragma unroll
        for (int i = 0; i < 6; ++i) {
            int gid = w * 6 + i;
            if (gid < 8) {
                gl_lds16(khi + kbK + (size_t)(gid * 16 + trow16) * C_ + kc + tquart,
                         (char*)sBhi + gid * 1024);
            } else if (gid < 16) {
                int g2 = gid - 8;
                gl_lds16(klo + kbK + (size_t)(g2 * 16 + trow16) * C_ + kc + tquart,
                         (char*)sBlo + g2 * 1024);
            } else if (gid < 20) {
                int g2 = gid - 16;
                gl_lds16(qkhi + kbA + (size_t)(g2 * 16 + trow16) * C_ + kc + tquart,
                         (char*)sAhi + g2 * 1024);
            } else {
                int g2 = gid - 20;
                gl_lds16(qklo + kbA + (size_t)(g2 * 16 + trow16) * C_ + kc + tquart,
                         (char*)sAlo + g2 * 1024);
            }
        }
        __syncthreads();
        bf16x8 ah[2], al[2];
#pragma unroll
        for (int tm = 0; tm < 2; ++tm) {
            int ar = (wm * 32 + tm * 16 + lm) * 32 + sw;
            ah[tm] = *(const bf16x8*)&sAhi[ar];
            al[tm] = *(const bf16x8*)&sAlo[ar];
        }
#pragma unroll
        for (int nt = 0; nt < 4; ++nt) {
            int nr = ((wn * 4 + nt) * 16 + lm) * 32 + sw;
            bf16x8 bh = *(const bf16x8*)&sBhi[nr];
            bf16x8 bl = *(const bf16x8*)&sBlo[nr];
#pragma unroll
            for (int tm = 0; tm < 2; ++tm) {
                acc[tm][nt] = __builtin_amdgcn_mfma_f32_16x16x32_bf16(ah[tm], bh, acc[tm][nt], 0, 0, 0);
                acc[tm][nt] = __builtin_amdgcn_mfma_f32_16x16x32_bf16(ah[tm], bl, acc[tm][nt], 0, 0, 0);
                acc[tm][nt] = __builtin_amdgcn_mfma_f32_16x16x32_bf16(al[tm], bh, acc[tm][nt], 0, 0, 0);
            }
        }
    }
    __syncthreads();

    float* rm1 = (float*)sBhi;   // scratch aliases sBhi; safe after final barrier
    float* rm2 = rm1 + 256;      // 2 wm-halves x 128 tokens
    int* ri1 = (int*)(rm2 + 256);
    int* ri2 = ri1 + 256;

#pragma unroll
    for (int nt = 0; nt < 4; ++nt) {
        float m1 = -3.4e38f, m2 = -3.4e38f; int i1 = 0, i2 = 0;
#pragma unroll
        for (int tm = 0; tm < 2; ++tm)
#pragma unroll
            for (int r = 0; r < 4; ++r) {
                float v = acc[tm][nt][r];
                int row = wm * 32 + tm * 16 + q4 * 4 + r;
                if (v > m1) { m2 = m1; i2 = i1; m1 = v; i1 = row; }
                else if (v > m2) { m2 = v; i2 = row; }
            }
#pragma unroll
        for (int off = 16; off < 64; off <<= 1) {
            float om1 = __shfl_xor(m1, off), om2 = __shfl_xor(m2, off);
            int oi1 = __shfl_xor(i1, off), oi2 = __shfl_xor(i2, off);
            bool take = (om1 > m1) || (om1 == m1 && oi1 < i1);
            float w1 = take ? om1 : m1; int wi1 = take ? oi1 : i1;
            float l1 = take ? m1 : om1; int li1 = take ? i1 : oi1;
            float s2 = m2; int si2 = i2;
            if (om2 > s2) { s2 = om2; si2 = oi2; }
            if (l1 > s2) { s2 = l1; si2 = li1; }
            m1 = w1; i1 = wi1; m2 = s2; i2 = si2;
        }
        if (q4 == 0) {
            int cw = (wn * 4 + nt) * 16 + lm;      // token col 0..127
            rm1[wm * 128 + cw] = m1; rm2[wm * 128 + cw] = m2;
            ri1[wm * 128 + cw] = i1; ri2[wm * 128 + cw] = i2;
        }
    }
    __syncthreads();
    if (tid < 128) {
        float a1 = rm1[tid], a2 = rm2[tid];
        int ai1 = ri1[tid], ai2 = ri2[tid];
        float b1 = rm1[128 + tid], b2 = rm2[128 + tid];
        int bi1 = ri1[128 + tid], bi2 = ri2[128 + tid];
        float w1, s2; int wi1, wi2;
        if (b1 > a1) { w1 = b1; wi1 = bi1; s2 = a1; wi2 = ai1; if (b2 > s2) { s2 = b2; wi2 = bi2; } }
        else         { w1 = a1; wi1 = ai1; s2 = a2; wi2 = ai2; if (b1 > s2) { s2 = b1; wi2 = bi1; } }
        idx[(size_t)(b * H_ + h) * S_ + s0 + tid] = (unsigned)wi1;
        if (w1 - s2 < TAU_) {
            unsigned p = atomicAdd(flag_cnt, 1u);
            if (p < LISTCAP) {
                unsigned tok = (unsigned)((b * H_ + h) * S_ + s0 + tid);
                flag_list[p] = tok | ((unsigned)wi1 << 19) | ((unsigned)wi2 << 25);
            }
        }
    }
}

// ---------------------------------------------------------------------------
// K3: fixup — exact fp32 recompute of two candidate rows for near-ties
// ---------------------------------------------------------------------------
__global__ __launch_bounds__(256) void fixup_kernel(const float* __restrict__ qk,
                                                    const float* __restrict__ key,
                                                    const unsigned int* __restrict__ flag_list,
                                                    const unsigned int* __restrict__ flag_cnt,
                                                    unsigned int* __restrict__ idx) {
    int w = threadIdx.x >> 6, l = threadIdx.x & 63;
    unsigned total = flag_cnt[0];
    if (total > LISTCAP) total = LISTCAP;
    for (unsigned t = blockIdx.x * 4 + w; t < total; t += gridDim.x * 4) {
        unsigned e = flag_list[t];
        unsigned tok = e & 0x7FFFFu;
        int i1 = (int)((e >> 19) & 63u), i2 = (int)((e >> 25) & 63u);
        unsigned bh = tok >> 12;
        unsigned s = tok & 4095u;
        unsigned bb = bh / H_;
        int l32 = l & 31;
        const float* qrow = qk + ((size_t)bh * N_ + (l < 32 ? i1 : i2)) * C_ + l32 * 12;
        const float* krow = key + ((size_t)bb * S_ + s) * C_ + l32 * 12;
        float sum = 0.f;
#pragma unroll
        for (int c = 0; c < 12; ++c) sum += qrow[c] * krow[c];
#pragma unroll
        for (int off = 1; off < 32; off <<= 1) sum += __shfl_xor(sum, off);
        float d1 = __shfl(sum, 0);
        float d2 = __shfl(sum, 32);
        int win = (d2 > d1 || (d2 == d1 && i2 < i1)) ? i2 : i1;
        if (l == 0) idx[(size_t)bh * S_ + s] = (unsigned)win;
    }
}

// ---------------------------------------------------------------------------
// K4: hist_build — per (b,h): histogram -> scan -> counting-sort placement
// ---------------------------------------------------------------------------
__global__ __launch_bounds__(256) void hist_build_kernel(const unsigned int* __restrict__ idx,
                                                         unsigned int* __restrict__ offs,
                                                         unsigned int* __restrict__ order) {
    __shared__ unsigned int cnts[N_];
    __shared__ unsigned int pos[N_];
    int tid = threadIdx.x;
    int bh = blockIdx.x;
    if (tid < N_) cnts[tid] = 0u;
    __syncthreads();
    const unsigned int* idxp = idx + (size_t)bh * S_;
    for (int s = tid; s < S_; s += 256) atomicAdd(&cnts[idxp[s]], 1u);
    __syncthreads();
    if (tid < N_) {
        unsigned v = cnts[tid];
        unsigned x = v;
#pragma unroll
        for (int off = 1; off < 64; off <<= 1) {
            unsigned y = __shfl_up(x, off);
            if (tid >= off) x += y;
        }
        unsigned excl = x - v;
        pos[tid] = excl;
        offs[(size_t)bh * 65 + tid] = excl;
        if (tid == 63) offs[(size_t)bh * 65 + 64] = x;   // == S_
    }
    __syncthreads();
    unsigned int* op = order + (size_t)bh * S_;
    for (int s = tid; s < S_; s += 256) {
        unsigned g = idxp[s];
        unsigned p = atomicAdd(&pos[g], 1u);
        op[p] = (unsigned)s;
    }
}

// ---------------------------------------------------------------------------
// K5+K6 fused: aggv (r5 structure, known-good 131us). ROUND-THIS: the only
// change is `#pragma unroll 4` on the inner gather loop — each iteration's
// 12B row-read depends only on a pre-loop shfl, so unrolling puts 4 L2
// gathers in flight and cuts the fat-group latency chain ~4x. Accumulation
// order unchanged (adds stay sequential) -> bit-identical output.
// ---------------------------------------------------------------------------
__global__ __launch_bounds__(256) void aggv_kernel(const unsigned short* __restrict__ khi,
                                                   const unsigned int* __restrict__ order,
                                                   const unsigned int* __restrict__ offs,
                                                   const float* __restrict__ Wv,
                                                   float* __restrict__ gvn) {
    __shared__ float lrows[4][C_];
    int tid = threadIdx.x;
    int w = tid >> 6, l = tid & 63;
    int h = blockIdx.y, b = blockIdx.z;
    int bh = b * H_ + h;
    int g = blockIdx.x * 2 + (w >> 1);   // 0..63
    int part = w & 1;
    unsigned beg = offs[(size_t)bh * 65 + g];
    unsigned end = offs[(size_t)bh * 65 + g + 1];
    int cnt = (int)(end - beg);
    float inv = 1.f / ((float)cnt + 1.f);
    const unsigned int* op = order + (size_t)bh * S_ + beg;
    const unsigned int* kbase = (const unsigned int*)(khi + (size_t)b * S_ * C_);
    float a0 = 0.f, a1 = 0.f, a2 = 0.f, a3 = 0.f, a4 = 0.f, a5 = 0.f;
    for (int base = part * 64; base < cnt; base += 128) {
        int m = cnt - base; if (m > 64) m = 64;
        unsigned sv = (l < m) ? op[base + l] : 0u;
#pragma unroll 4
        for (int i = 0; i < m; ++i) {
            int s = (int)__shfl((int)sv, i);
            const unsigned int* kp = kbase + (size_t)s * (C_ / 2) + l * 3;
            unsigned u0 = kp[0], u1 = kp[1], u2 = kp[2];
            a0 += bfu_lo(u0); a1 += bfu_hi(u0);
            a2 += bfu_lo(u1); a3 += bfu_hi(u1);
            a4 += bfu_lo(u2); a5 += bfu_hi(u2);
        }
    }
    float* lp = &lrows[w][l * 6];
    lp[0] = a0 * inv; lp[1] = a1 * inv; lp[2] = a2 * inv;
    lp[3] = a3 * inv; lp[4] = a4 * inv; lp[5] = a5 * inv;
    __syncthreads();
    if (part == 0) {
        // phase B == old gv: z = x + y per float4, then per-c4 dot with Wv row
        const float4* s0 = (const float4*)lrows[w];
        const float4* s1 = (const float4*)lrows[w + 1];
        const float* wrow = Wv + (size_t)(h * DH_ + l) * C_;
        float acc = 0.f;
#pragma unroll 8
        for (int c4 = 0; c4 < C_ / 4; ++c4) {
            float4 x = s0[c4];
            float4 y = s1[c4];
            float4 z = { x.x + y.x, x.y + y.y, x.z + y.z, x.w + y.w };
            float4 wv = *(const float4*)&wrow[c4 * 4];
            acc += z.x * wv.x + z.y * wv.y + z.z * wv.z + z.w * wv.w;
        }
        gvn[((size_t)bh * N_ + g) * DH_ + l] = acc;
    }
}

// ---------------------------------------------------------------------------
// K7: out — 4 tokens per block (r4 state, known-good)
// ---------------------------------------------------------------------------
__global__ __launch_bounds__(384) void out_kernel(const float* __restrict__ gvn,
                                                  const float* __restrict__ Wp,
                                                  const float* __restrict__ bp,
                                                  float* __restrict__ out) {
    __shared__ float vals[4][C_];
    int blk = blockIdx.x;                 // 0..255
    int b = blk >> 4, n0 = (blk & 15) * 4;
    int t = threadIdx.x;
    int h = t >> 6, d = t & 63;
#pragma unroll
    for (int j = 0; j < 4; ++j)
        vals[j][t] = gvn[((size_t)(b * H_ + h) * N_ + n0 + j) * DH_ + d];
    __syncthreads();
    const float4* w4 = (const float4*)(Wp + (size_t)t * C_);
    float s0 = bp[t], s1 = s0, s2 = s0, s3 = s0;
    const float4* v0 = (const float4*)vals[0];
    const float4* v1 = (const float4*)vals[1];
    const float4* v2 = (const float4*)vals[2];
    const float4* v3 = (const float4*)vals[3];
#pragma unroll 4
    for (int i = 0; i < C_ / 4; ++i) {
        float4 w = w4[i];
        float4 a0 = v0[i]; s0 += a0.x * w.x + a0.y * w.y + a0.z * w.z + a0.w * w.w;
        float4 a1 = v1[i]; s1 += a1.x * w.x + a1.y * w.y + a1.z * w.z + a1.w * w.w;
        float4 a2 = v2[i]; s2 += a2.x * w.x + a2.y * w.y + a2.z * w.z + a2.w * w.w;
        float4 a3 = v3[i]; s3 += a3.x * w.x + a3.y * w.y + a3.z * w.z + a3.w * w.w;
    }
    size_t ob = ((size_t)b * N_ + n0) * C_ + t;
    out[ob] = s0;
    out[ob + C_] = s1;
    out[ob + 2 * C_] = s2;
    out[ob + 3 * C_] = s3;
}

// ---------------------------------------------------------------------------
extern "C" void kernel_launch(void* const* d_in, const int* in_sizes, int n_in,
                              void* d_out, int out_size, void* d_ws, size_t ws_size,
                              hipStream_t stream) {
    (void)in_sizes; (void)n_in; (void)out_size; (void)ws_size;
    const float* query = (const float*)d_in[0];
    const float* key   = (const float*)d_in[1];
    const float* Wq    = (const float*)d_in[2];
    const float* Wk    = (const float*)d_in[3];
    const float* Wv    = (const float*)d_in[4];
    const float* Wp    = (const float*)d_in[5];
    const float* bp    = (const float*)d_in[6];
    float* out = (float*)d_out;

    char* ws = (char*)d_ws;
    size_t off = 0;
    unsigned short* khi  = (unsigned short*)(ws + off); off += (size_t)B_ * S_ * C_ * 2;
    unsigned short* klo  = (unsigned short*)(ws + off); off += (size_t)B_ * S_ * C_ * 2;
    float* qk            = (float*)(ws + off);          off += (size_t)B_ * H_ * N_ * C_ * 4;
    unsigned short* qkhi = (unsigned short*)(ws + off); off += (size_t)B_ * H_ * N_ * C_ * 2;
    unsigned short* qklo = (unsigned short*)(ws + off); off += (size_t)B_ * H_ * N_ * C_ * 2;
    unsigned int* idx    = (unsigned int*)(ws + off);   off += (size_t)B_ * H_ * S_ * 4;
    unsigned int* order  = (unsigned int*)(ws + off);   off += (size_t)B_ * H_ * S_ * 4;
    unsigned int* offs   = (unsigned int*)(ws + off);   off += (size_t)B_ * H_ * 65 * 4;
    float* gvn           = (float*)(ws + off);          off += (size_t)B_ * H_ * N_ * DH_ * 4;
    unsigned int* fcnt   = (unsigned int*)(ws + off);   off += 256;
    unsigned int* flist  = (unsigned int*)(ws + off);   off += (size_t)LISTCAP * 4;

    hipMemsetAsync(fcnt, 0, 256, stream);

    prepqk_kernel<<<PREP_BLOCKS + QK_BLOCKS, 384, 0, stream>>>(key, khi, klo,
                                                               query, Wq, Wk, qk, qkhi, qklo);
    attn_kernel<<<dim3(S_ / 128, H_, B_), 256, 0, stream>>>(qkhi, qklo, khi, klo, idx, fcnt, flist);
    fixup_kernel<<<256, 256, 0, stream>>>(qk, key, flist, fcnt, idx);
    hist_build_kernel<<<B_ * H_, 256, 0, stream>>>(idx, offs, order);
    aggv_kernel<<<dim3(32, H_, B_), 256, 0, stream>>>(khi, order, offs, Wv, gvn);
    out_kernel<<<B_ * N_ / 4, 384, 0, stream>>>(gvn, Wp, bp, out);
}

// Round 8
// 449.890 us; speedup vs baseline: 1.1950x; 1.0735x over previous
//
#include <hip/hip_runtime.h>
#include <hip/hip_bf16.h>
#include <stdint.h>

#define B_ 16
#define N_ 64
#define S_ 4096
#define C_ 384
#define H_ 6
#define DH_ 64
#define SCALE_ 0.125f
#define TAU_ 2e-4f
#define LISTCAP 262144

typedef __attribute__((ext_vector_type(8))) short bf16x8;
typedef __attribute__((ext_vector_type(4))) float f32x4;

static __device__ __forceinline__ unsigned short f2bf(float x) {
    union { float f; unsigned u; } v; v.f = x;
    unsigned r = v.u + 0x7FFFu + ((v.u >> 16) & 1u);
    return (unsigned short)(r >> 16);
}
static __device__ __forceinline__ float bf2f(unsigned short b) {
    union { unsigned u; float f; } v; v.u = ((unsigned)b) << 16; return v.f;
}
static __device__ __forceinline__ float bfu_lo(unsigned u) {
    union { unsigned u; float f; } v; v.u = u << 16; return v.f;
}
static __device__ __forceinline__ float bfu_hi(unsigned u) {
    union { unsigned u; float f; } v; v.u = u & 0xFFFF0000u; return v.f;
}

// async global->LDS, 16B/lane; LDS dest = wave-uniform base + lane*16
static __device__ __forceinline__ void gl_lds16(const void* g, void* l) {
    __builtin_amdgcn_global_load_lds(
        (const __attribute__((address_space(1))) unsigned int*)g,
        (__attribute__((address_space(3))) unsigned int*)l, 16, 0, 0);
}

// ---------------------------------------------------------------------------
// K0+K1 fused: prep (key -> khi/klo) + q-proj/fold-Wk. (r7 state: vectorized
// stores via LDS transpose — confirmed, dropped out of top-5)
// ---------------------------------------------------------------------------
#define PREP_BLOCKS 8192   // 8192 * 384 threads * 8 elems = 16*4096*384
#define QK_BLOCKS   (8 * H_ * B_)   // N_/8 x H x B = 768

__global__ __launch_bounds__(384) void prepqk_kernel(const float* __restrict__ key,
                                                     unsigned short* __restrict__ khi,
                                                     unsigned short* __restrict__ klo,
                                                     const float* __restrict__ query,
                                                     const float* __restrict__ Wq,
                                                     const float* __restrict__ Wk,
                                                     float* __restrict__ qk,
                                                     unsigned short* __restrict__ qkhi,
                                                     unsigned short* __restrict__ qklo) {
    if (blockIdx.x < PREP_BLOCKS) {
        size_t gid = (size_t)blockIdx.x * 384 + threadIdx.x;
        size_t base = gid * 8;
        float4 x0 = *(const float4*)(key + base);
        float4 x1 = *(const float4*)(key + base + 4);
        float xs[8] = { x0.x, x0.y, x0.z, x0.w, x1.x, x1.y, x1.z, x1.w };
        unsigned short hi[8], lo[8];
#pragma unroll
        for (int i = 0; i < 8; ++i) {
            hi[i] = f2bf(xs[i]);
            lo[i] = f2bf(xs[i] - bf2f(hi[i]));
        }
        *(bf16x8*)(khi + base) = *(bf16x8*)hi;
        *(bf16x8*)(klo + base) = *(bf16x8*)lo;
        return;
    }
    // ---- qk part ----
    __shared__ float qstage[8][C_];   // phase 1: staged query rows; phase 2: transpose buffer
    __shared__ float qv[8][DH_];
    int e = blockIdx.x - PREP_BLOCKS;           // 0..767
    int ng = e & 7;                             // 8 row-tiles
    int h = (e >> 3) % H_;
    int b = e / (8 * H_);
    int t = threadIdx.x;
    int n0 = ng * 8;
#pragma unroll
    for (int i = 0; i < 8; ++i)
        qstage[i][t] = query[((size_t)(b * N_ + n0 + i)) * C_ + t];
    __syncthreads();
    if (t < 256) {
        int i0 = t >> 6, d = t & 63;
        const float4* wq = (const float4*)(Wq + (size_t)(h * DH_ + d) * C_);
        float accA = 0.f, accB = 0.f;
#pragma unroll 4
        for (int c4 = 0; c4 < C_ / 4; ++c4) {
            float4 w = wq[c4];
            float4 qa = *(const float4*)&qstage[i0][c4 * 4];
            float4 qb = *(const float4*)&qstage[i0 + 4][c4 * 4];
            accA += qa.x * w.x + qa.y * w.y + qa.z * w.z + qa.w * w.w;
            accB += qb.x * w.x + qb.y * w.y + qb.z * w.z + qb.w * w.w;
        }
        qv[i0][d] = accA * SCALE_;
        qv[i0 + 4][d] = accB * SCALE_;
    }
    __syncthreads();
    float a[8];
#pragma unroll
    for (int i = 0; i < 8; ++i) a[i] = 0.f;
    {
        const float* wk = Wk + (size_t)h * DH_ * C_ + t;
#pragma unroll 4
        for (int d = 0; d < DH_; ++d) {
            float w = wk[(size_t)d * C_];
#pragma unroll
            for (int i = 0; i < 8; ++i) a[i] += qv[i][d] * w;
        }
    }
#pragma unroll
    for (int i = 0; i < 8; ++i) qstage[i][t] = a[i];
    __syncthreads();
    {
        int r = t / 48, c0 = (t % 48) * 8;
        float v[8];
#pragma unroll
        for (int j = 0; j < 8; ++j) v[j] = qstage[r][c0 + j];
        unsigned short hi[8], lo[8];
#pragma unroll
        for (int j = 0; j < 8; ++j) {
            hi[j] = f2bf(v[j]);
            lo[j] = f2bf(v[j] - bf2f(hi[j]));
        }
        size_t o = ((size_t)(b * H_ + h) * N_ + n0 + r) * C_ + c0;
        float4 f0 = { v[0], v[1], v[2], v[3] };
        float4 f1 = { v[4], v[5], v[6], v[7] };
        *(float4*)(qk + o) = f0;
        *(float4*)(qk + o + 4) = f1;
        *(bf16x8*)(qkhi + o) = *(bf16x8*)hi;
        *(bf16x8*)(qklo + o) = *(bf16x8*)lo;
    }
}

// ---------------------------------------------------------------------------
// K2: logits via 3-pass bf16 MFMA + argmax. 64n x 128 tokens per block.
// (round-3 state, known-good)
// ---------------------------------------------------------------------------
__global__ __launch_bounds__(256) void attn_kernel(const unsigned short* __restrict__ qkhi,
                                                   const unsigned short* __restrict__ qklo,
                                                   const unsigned short* __restrict__ khi,
                                                   const unsigned short* __restrict__ klo,
                                                   unsigned int* __restrict__ idx,
                                                   unsigned int* __restrict__ flag_cnt,
                                                   unsigned int* __restrict__ flag_list) {
    __shared__ __align__(16) unsigned short sAhi[64 * 32];
    __shared__ __align__(16) unsigned short sAlo[64 * 32];
    __shared__ __align__(16) unsigned short sBhi[128 * 32];
    __shared__ __align__(16) unsigned short sBlo[128 * 32];
    int tid = threadIdx.x;
    int w = tid >> 6, l = tid & 63;          // w in 0..3
    int wm = w >> 1, wn = w & 1;             // 2 x 2 wave grid (32q x 64tok each)
    int q4 = l >> 4, lm = l & 15;
    int s0 = blockIdx.x * 128;
    int h = blockIdx.y, b = blockIdx.z;
    size_t kbK = ((size_t)b * S_ + s0) * C_;
    size_t kbA = (size_t)(b * H_ + h) * N_ * C_;
    int trow16 = l >> 2;
    int tquart = ((l & 3) ^ ((l >> 3) & 3)) * 8;
    int sw = (q4 ^ ((lm >> 1) & 3)) * 8;

    f32x4 acc[2][4];
#pragma unroll
    for (int tm = 0; tm < 2; ++tm)
#pragma unroll
        for (int nt = 0; nt < 4; ++nt) acc[tm][nt] = (f32x4)0.f;

    for (int kc = 0; kc < C_; kc += 32) {
        __syncthreads();
#pragma unroll
        for (int i = 0; i < 6; ++i) {
            int gid = w * 6 + i;
            if (gid < 8) {
                gl_lds16(khi + kbK + (size_t)(gid * 16 + trow16) * C_ + kc + tquart,
                         (char*)sBhi + gid * 1024);
            } else if (gid < 16) {
                int g2 = gid - 8;
                gl_lds16(klo + kbK + (size_t)(g2 * 16 + trow16) * C_ + kc + tquart,
                         (char*)sBlo + g2 * 1024);
            } else if (gid < 20) {
                int g2 = gid - 16;
                gl_lds16(qkhi + kbA + (size_t)(g2 * 16 + trow16) * C_ + kc + tquart,
                         (char*)sAhi + g2 * 1024);
            } else {
                int g2 = gid - 20;
                gl_lds16(qklo + kbA + (size_t)(g2 * 16 + trow16) * C_ + kc + tquart,
                         (char*)sAlo + g2 * 1024);
            }
        }
        __syncthreads();
        bf16x8 ah[2], al[2];
#pragma unroll
        for (int tm = 0; tm < 2; ++tm) {
            int ar = (wm * 32 + tm * 16 + lm) * 32 + sw;
            ah[tm] = *(const bf16x8*)&sAhi[ar];
            al[tm] = *(const bf16x8*)&sAlo[ar];
        }
#pragma unroll
        for (int nt = 0; nt < 4; ++nt) {
            int nr = ((wn * 4 + nt) * 16 + lm) * 32 + sw;
            bf16x8 bh = *(const bf16x8*)&sBhi[nr];
            bf16x8 bl = *(const bf16x8*)&sBlo[nr];
#pragma unroll
            for (int tm = 0; tm < 2; ++tm) {
                acc[tm][nt] = __builtin_amdgcn_mfma_f32_16x16x32_bf16(ah[tm], bh, acc[tm][nt], 0, 0, 0);
                acc[tm][nt] = __builtin_amdgcn_mfma_f32_16x16x32_bf16(ah[tm], bl, acc[tm][nt], 0, 0, 0);
                acc[tm][nt] = __builtin_amdgcn_mfma_f32_16x16x32_bf16(al[tm], bh, acc[tm][nt], 0, 0, 0);
            }
        }
    }
    __syncthreads();

    float* rm1 = (float*)sBhi;   // scratch aliases sBhi; safe after final barrier
    float* rm2 = rm1 + 256;      // 2 wm-halves x 128 tokens
    int* ri1 = (int*)(rm2 + 256);
    int* ri2 = ri1 + 256;

#pragma unroll
    for (int nt = 0; nt < 4; ++nt) {
        float m1 = -3.4e38f, m2 = -3.4e38f; int i1 = 0, i2 = 0;
#pragma unroll
        for (int tm = 0; tm < 2; ++tm)
#pragma unroll
            for (int r = 0; r < 4; ++r) {
                float v = acc[tm][nt][r];
                int row = wm * 32 + tm * 16 + q4 * 4 + r;
                if (v > m1) { m2 = m1; i2 = i1; m1 = v; i1 = row; }
                else if (v > m2) { m2 = v; i2 = row; }
            }
#pragma unroll
        for (int off = 16; off < 64; off <<= 1) {
            float om1 = __shfl_xor(m1, off), om2 = __shfl_xor(m2, off);
            int oi1 = __shfl_xor(i1, off), oi2 = __shfl_xor(i2, off);
            bool take = (om1 > m1) || (om1 == m1 && oi1 < i1);
            float w1 = take ? om1 : m1; int wi1 = take ? oi1 : i1;
            float l1 = take ? m1 : om1; int li1 = take ? i1 : oi1;
            float s2 = m2; int si2 = i2;
            if (om2 > s2) { s2 = om2; si2 = oi2; }
            if (l1 > s2) { s2 = l1; si2 = li1; }
            m1 = w1; i1 = wi1; m2 = s2; i2 = si2;
        }
        if (q4 == 0) {
            int cw = (wn * 4 + nt) * 16 + lm;      // token col 0..127
            rm1[wm * 128 + cw] = m1; rm2[wm * 128 + cw] = m2;
            ri1[wm * 128 + cw] = i1; ri2[wm * 128 + cw] = i2;
        }
    }
    __syncthreads();
    if (tid < 128) {
        float a1 = rm1[tid], a2 = rm2[tid];
        int ai1 = ri1[tid], ai2 = ri2[tid];
        float b1 = rm1[128 + tid], b2 = rm2[128 + tid];
        int bi1 = ri1[128 + tid], bi2 = ri2[128 + tid];
        float w1, s2; int wi1, wi2;
        if (b1 > a1) { w1 = b1; wi1 = bi1; s2 = a1; wi2 = ai1; if (b2 > s2) { s2 = b2; wi2 = bi2; } }
        else         { w1 = a1; wi1 = ai1; s2 = a2; wi2 = ai2; if (b1 > s2) { s2 = b1; wi2 = bi1; } }
        idx[(size_t)(b * H_ + h) * S_ + s0 + tid] = (unsigned)wi1;
        if (w1 - s2 < TAU_) {
            unsigned p = atomicAdd(flag_cnt, 1u);
            if (p < LISTCAP) {
                unsigned tok = (unsigned)((b * H_ + h) * S_ + s0 + tid);
                flag_list[p] = tok | ((unsigned)wi1 << 19) | ((unsigned)wi2 << 25);
            }
        }
    }
}

// ---------------------------------------------------------------------------
// K3: fixup — exact fp32 recompute of two candidate rows for near-ties
// ---------------------------------------------------------------------------
__global__ __launch_bounds__(256) void fixup_kernel(const float* __restrict__ qk,
                                                    const float* __restrict__ key,
                                                    const unsigned int* __restrict__ flag_list,
                                                    const unsigned int* __restrict__ flag_cnt,
                                                    unsigned int* __restrict__ idx) {
    int w = threadIdx.x >> 6, l = threadIdx.x & 63;
    unsigned total = flag_cnt[0];
    if (total > LISTCAP) total = LISTCAP;
    for (unsigned t = blockIdx.x * 4 + w; t < total; t += gridDim.x * 4) {
        unsigned e = flag_list[t];
        unsigned tok = e & 0x7FFFFu;
        int i1 = (int)((e >> 19) & 63u), i2 = (int)((e >> 25) & 63u);
        unsigned bh = tok >> 12;
        unsigned s = tok & 4095u;
        unsigned bb = bh / H_;
        int l32 = l & 31;
        const float* qrow = qk + ((size_t)bh * N_ + (l < 32 ? i1 : i2)) * C_ + l32 * 12;
        const float* krow = key + ((size_t)bb * S_ + s) * C_ + l32 * 12;
        float sum = 0.f;
#pragma unroll
        for (int c = 0; c < 12; ++c) sum += qrow[c] * krow[c];
#pragma unroll
        for (int off = 1; off < 32; off <<= 1) sum += __shfl_xor(sum, off);
        float d1 = __shfl(sum, 0);
        float d2 = __shfl(sum, 32);
        int win = (d2 > d1 || (d2 == d1 && i2 < i1)) ? i2 : i1;
        if (l == 0) idx[(size_t)bh * S_ + s] = (unsigned)win;
    }
}

// ---------------------------------------------------------------------------
// K4: hist_build — per (b,h): histogram -> scan -> counting-sort placement
// ---------------------------------------------------------------------------
__global__ __launch_bounds__(256) void hist_build_kernel(const unsigned int* __restrict__ idx,
                                                         unsigned int* __restrict__ offs,
                                                         unsigned int* __restrict__ order) {
    __shared__ unsigned int cnts[N_];
    __shared__ unsigned int pos[N_];
    int tid = threadIdx.x;
    int bh = blockIdx.x;
    if (tid < N_) cnts[tid] = 0u;
    __syncthreads();
    const unsigned int* idxp = idx + (size_t)bh * S_;
    for (int s = tid; s < S_; s += 256) atomicAdd(&cnts[idxp[s]], 1u);
    __syncthreads();
    if (tid < N_) {
        unsigned v = cnts[tid];
        unsigned x = v;
#pragma unroll
        for (int off = 1; off < 64; off <<= 1) {
            unsigned y = __shfl_up(x, off);
            if (tid >= off) x += y;
        }
        unsigned excl = x - v;
        pos[tid] = excl;
        offs[(size_t)bh * 65 + tid] = excl;
        if (tid == 63) offs[(size_t)bh * 65 + 64] = x;   // == S_
    }
    __syncthreads();
    unsigned int* op = order + (size_t)bh * S_;
    for (int s = tid; s < S_; s += 256) {
        unsigned g = idxp[s];
        unsigned p = atomicAdd(&pos[g], 1u);
        op[p] = (unsigned)s;
    }
}

// ---------------------------------------------------------------------------
// K5+K6 fused: aggv — skew fix, round 2. r7 post-mortem: unroll pragma on
// the runtime gather loop didn't break the shfl->wait->load->wait->add serial
// chain; fat-group wave still ~2000 x L2-latency = 131us. This round:
// (a) 8 PARTS per group (one block = 8 waves = ONE group; fat-group serial
//     length 2048 -> 512 tokens/wave), partials combined through LDS;
// (b) manual 8-wide batching: hoist 8 shfls, issue 24 independent loads,
//     then accumulate in original token order (MLP ~8 rows in flight).
// Per-part token accumulation order unchanged; part split 2->8 changes only
// the fp32 partial-sum grouping (same rounding class as r5's split).
// ---------------------------------------------------------------------------
#define AGG_PARTS 8
__global__ __launch_bounds__(512) void aggv_kernel(const unsigned short* __restrict__ khi,
                                                   const unsigned int* __restrict__ order,
                                                   const unsigned int* __restrict__ offs,
                                                   const float* __restrict__ Wv,
                                                   float* __restrict__ gvn) {
    __shared__ float lrows[AGG_PARTS][C_];
    int tid = threadIdx.x;
    int part = tid >> 6, l = tid & 63;       // part = wave id 0..7
    int h = blockIdx.y, b = blockIdx.z;
    int bh = b * H_ + h;
    int g = blockIdx.x;                      // one group per block
    unsigned beg = offs[(size_t)bh * 65 + g];
    unsigned end = offs[(size_t)bh * 65 + g + 1];
    int cnt = (int)(end - beg);
    float inv = 1.f / ((float)cnt + 1.f);
    const unsigned int* op = order + (size_t)bh * S_ + beg;
    const unsigned int* kbase = (const unsigned int*)(khi + (size_t)b * S_ * C_);
    float a0 = 0.f, a1 = 0.f, a2 = 0.f, a3 = 0.f, a4 = 0.f, a5 = 0.f;
    for (int base = part * 64; base < cnt; base += 64 * AGG_PARTS) {
        int m = cnt - base; if (m > 64) m = 64;
        unsigned sv = (l < m) ? op[base + l] : 0u;
        int i = 0;
        for (; i + 8 <= m; i += 8) {
            int ss[8];
#pragma unroll
            for (int j = 0; j < 8; ++j) ss[j] = __shfl((int)sv, i + j);
            unsigned u[8][3];
#pragma unroll
            for (int j = 0; j < 8; ++j) {
                const unsigned int* kp = kbase + (size_t)ss[j] * (C_ / 2) + l * 3;
                u[j][0] = kp[0]; u[j][1] = kp[1]; u[j][2] = kp[2];
            }
#pragma unroll
            for (int j = 0; j < 8; ++j) {
                a0 += bfu_lo(u[j][0]); a1 += bfu_hi(u[j][0]);
                a2 += bfu_lo(u[j][1]); a3 += bfu_hi(u[j][1]);
                a4 += bfu_lo(u[j][2]); a5 += bfu_hi(u[j][2]);
            }
        }
        for (; i < m; ++i) {
            int s = (int)__shfl((int)sv, i);
            const unsigned int* kp = kbase + (size_t)s * (C_ / 2) + l * 3;
            unsigned u0 = kp[0], u1 = kp[1], u2 = kp[2];
            a0 += bfu_lo(u0); a1 += bfu_hi(u0);
            a2 += bfu_lo(u1); a3 += bfu_hi(u1);
            a4 += bfu_lo(u2); a5 += bfu_hi(u2);
        }
    }
    float* lp = &lrows[part][l * 6];
    lp[0] = a0 * inv; lp[1] = a1 * inv; lp[2] = a2 * inv;
    lp[3] = a3 * inv; lp[4] = a4 * inv; lp[5] = a5 * inv;
    __syncthreads();
    if (part == 0) {
        // combine 8 partial rows (sequential p order) + dot with Wv row
        const float* wrow = Wv + (size_t)(h * DH_ + l) * C_;
        float acc = 0.f;
#pragma unroll 4
        for (int c4 = 0; c4 < C_ / 4; ++c4) {
            float4 z = *(const float4*)&lrows[0][c4 * 4];
#pragma unroll
            for (int p = 1; p < AGG_PARTS; ++p) {
                float4 y = *(const float4*)&lrows[p][c4 * 4];
                z.x += y.x; z.y += y.y; z.z += y.z; z.w += y.w;
            }
            float4 wv = *(const float4*)&wrow[c4 * 4];
            acc += z.x * wv.x + z.y * wv.y + z.z * wv.z + z.w * wv.w;
        }
        gvn[((size_t)bh * N_ + g) * DH_ + l] = acc;
    }
}

// ---------------------------------------------------------------------------
// K7: out — 4 tokens per block (r4 state, known-good)
// ---------------------------------------------------------------------------
__global__ __launch_bounds__(384) void out_kernel(const float* __restrict__ gvn,
                                                  const float* __restrict__ Wp,
                                                  const float* __restrict__ bp,
                                                  float* __restrict__ out) {
    __shared__ float vals[4][C_];
    int blk = blockIdx.x;                 // 0..255
    int b = blk >> 4, n0 = (blk & 15) * 4;
    int t = threadIdx.x;
    int h = t >> 6, d = t & 63;
#pragma unroll
    for (int j = 0; j < 4; ++j)
        vals[j][t] = gvn[((size_t)(b * H_ + h) * N_ + n0 + j) * DH_ + d];
    __syncthreads();
    const float4* w4 = (const float4*)(Wp + (size_t)t * C_);
    float s0 = bp[t], s1 = s0, s2 = s0, s3 = s0;
    const float4* v0 = (const float4*)vals[0];
    const float4* v1 = (const float4*)vals[1];
    const float4* v2 = (const float4*)vals[2];
    const float4* v3 = (const float4*)vals[3];
#pragma unroll 4
    for (int i = 0; i < C_ / 4; ++i) {
        float4 w = w4[i];
        float4 a0 = v0[i]; s0 += a0.x * w.x + a0.y * w.y + a0.z * w.z + a0.w * w.w;
        float4 a1 = v1[i]; s1 += a1.x * w.x + a1.y * w.y + a1.z * w.z + a1.w * w.w;
        float4 a2 = v2[i]; s2 += a2.x * w.x + a2.y * w.y + a2.z * w.z + a2.w * w.w;
        float4 a3 = v3[i]; s3 += a3.x * w.x + a3.y * w.y + a3.z * w.z + a3.w * w.w;
    }
    size_t ob = ((size_t)b * N_ + n0) * C_ + t;
    out[ob] = s0;
    out[ob + C_] = s1;
    out[ob + 2 * C_] = s2;
    out[ob + 3 * C_] = s3;
}

// ---------------------------------------------------------------------------
extern "C" void kernel_launch(void* const* d_in, const int* in_sizes, int n_in,
                              void* d_out, int out_size, void* d_ws, size_t ws_size,
                              hipStream_t stream) {
    (void)in_sizes; (void)n_in; (void)out_size; (void)ws_size;
    const float* query = (const float*)d_in[0];
    const float* key   = (const float*)d_in[1];
    const float* Wq    = (const float*)d_in[2];
    const float* Wk    = (const float*)d_in[3];
    const float* Wv    = (const float*)d_in[4];
    const float* Wp    = (const float*)d_in[5];
    const float* bp    = (const float*)d_in[6];
    float* out = (float*)d_out;

    char* ws = (char*)d_ws;
    size_t off = 0;
    unsigned short* khi  = (unsigned short*)(ws + off); off += (size_t)B_ * S_ * C_ * 2;
    unsigned short* klo  = (unsigned short*)(ws + off); off += (size_t)B_ * S_ * C_ * 2;
    float* qk            = (float*)(ws + off);          off += (size_t)B_ * H_ * N_ * C_ * 4;
    unsigned short* qkhi = (unsigned short*)(ws + off); off += (size_t)B_ * H_ * N_ * C_ * 2;
    unsigned short* qklo = (unsigned short*)(ws + off); off += (size_t)B_ * H_ * N_ * C_ * 2;
    unsigned int* idx    = (unsigned int*)(ws + off);   off += (size_t)B_ * H_ * S_ * 4;
    unsigned int* order  = (unsigned int*)(ws + off);   off += (size_t)B_ * H_ * S_ * 4;
    unsigned int* offs   = (unsigned int*)(ws + off);   off += (size_t)B_ * H_ * 65 * 4;
    float* gvn           = (float*)(ws + off);          off += (size_t)B_ * H_ * N_ * DH_ * 4;
    unsigned int* fcnt   = (unsigned int*)(ws + off);   off += 256;
    unsigned int* flist  = (unsigned int*)(ws + off);   off += (size_t)LISTCAP * 4;

    hipMemsetAsync(fcnt, 0, 256, stream);

    prepqk_kernel<<<PREP_BLOCKS + QK_BLOCKS, 384, 0, stream>>>(key, khi, klo,
                                                               query, Wq, Wk, qk, qkhi, qklo);
    attn_kernel<<<dim3(S_ / 128, H_, B_), 256, 0, stream>>>(qkhi, qklo, khi, klo, idx, fcnt, flist);
    fixup_kernel<<<256, 256, 0, stream>>>(qk, key, flist, fcnt, idx);
    hist_build_kernel<<<B_ * H_, 256, 0, stream>>>(idx, offs, order);
    aggv_kernel<<<dim3(N_, H_, B_), 512, 0, stream>>>(khi, order, offs, Wv, gvn);
    out_kernel<<<B_ * N_ / 4, 384, 0, stream>>>(gvn, Wp, bp, out);
}

// Round 9
// 402.307 us; speedup vs baseline: 1.3363x; 1.1183x over previous
//
#include <hip/hip_runtime.h>
#include <hip/hip_bf16.h>
#include <stdint.h>

#define B_ 16
#define N_ 64
#define S_ 4096
#define C_ 384
#define H_ 6
#define DH_ 64
#define SCALE_ 0.125f
#define TAU_ 2e-4f
#define LISTCAP 262144

typedef __attribute__((ext_vector_type(8))) short bf16x8;
typedef __attribute__((ext_vector_type(4))) float f32x4;
typedef __attribute__((ext_vector_type(4))) unsigned short u16x4;

static __device__ __forceinline__ unsigned short f2bf(float x) {
    union { float f; unsigned u; } v; v.f = x;
    unsigned r = v.u + 0x7FFFu + ((v.u >> 16) & 1u);
    return (unsigned short)(r >> 16);
}
static __device__ __forceinline__ float bf2f(unsigned short b) {
    union { unsigned u; float f; } v; v.u = ((unsigned)b) << 16; return v.f;
}
static __device__ __forceinline__ float bfu_lo(unsigned u) {
    union { unsigned u; float f; } v; v.u = u << 16; return v.f;
}
static __device__ __forceinline__ float bfu_hi(unsigned u) {
    union { unsigned u; float f; } v; v.u = u & 0xFFFF0000u; return v.f;
}

// async global->LDS, 16B/lane; LDS dest = wave-uniform base + lane*16
static __device__ __forceinline__ void gl_lds16(const void* g, void* l) {
    __builtin_amdgcn_global_load_lds(
        (const __attribute__((address_space(1))) unsigned int*)g,
        (__attribute__((address_space(3))) unsigned int*)l, 16, 0, 0);
}

// ---------------------------------------------------------------------------
// K0+K1 fused: prep + qk + (NEW) Wp/Wv transpose tiles.
// ROUND-THIS: (a) prep loads were 32B/lane-strided; now fully coalesced
// 16B/lane float4 loads + 8B/lane ushort4 stores — bit-identical bytes.
// (b) 72 transpose blocks build WpT/WvT for the post-argmax consumers
// (out, aggv) to kill their row-per-thread strided reads. qk part unchanged
// (argmax-sensitive; if prepqk stays ~115 the qk interior is isolated as
// the residual -> next round).
// ---------------------------------------------------------------------------
#define PREP_BLOCKS 8192   // 8192 * 3072 elems = 16*4096*384
#define QK_BLOCKS   (8 * H_ * B_)   // 768
#define TR_BLOCKS   72              // 2 matrices x 36 (64x64) tiles

__global__ __launch_bounds__(384) void prepqk_kernel(const float* __restrict__ key,
                                                     unsigned short* __restrict__ khi,
                                                     unsigned short* __restrict__ klo,
                                                     const float* __restrict__ query,
                                                     const float* __restrict__ Wq,
                                                     const float* __restrict__ Wk,
                                                     float* __restrict__ qk,
                                                     unsigned short* __restrict__ qkhi,
                                                     unsigned short* __restrict__ qklo,
                                                     const float* __restrict__ Wp,
                                                     const float* __restrict__ Wv,
                                                     float* __restrict__ wpT,
                                                     float* __restrict__ wvT) {
    __shared__ float qstage[8][C_];   // qk: staged query rows / transpose buffer
    __shared__ float qv[8][DH_];
    __shared__ float trt[64][65];     // transpose tile
    int t = threadIdx.x;
    if (blockIdx.x < PREP_BLOCKS) {
        size_t blk = (size_t)blockIdx.x * 3072;
#pragma unroll
        for (int half = 0; half < 2; ++half) {
            size_t base = blk + (size_t)half * 1536 + (size_t)t * 4;
            float4 x = *(const float4*)(key + base);
            float xs[4] = { x.x, x.y, x.z, x.w };
            unsigned short hi[4], lo[4];
#pragma unroll
            for (int i = 0; i < 4; ++i) {
                hi[i] = f2bf(xs[i]);
                lo[i] = f2bf(xs[i] - bf2f(hi[i]));
            }
            *(u16x4*)(khi + base) = *(u16x4*)hi;
            *(u16x4*)(klo + base) = *(u16x4*)lo;
        }
        return;
    }
    int e = blockIdx.x - PREP_BLOCKS;
    if (e >= QK_BLOCKS) {
        // ---- transpose part: WpT[c][j] = Wp[j][c], WvT likewise ----
        int e2 = e - QK_BLOCKS;                 // 0..71
        const float* src = (e2 < 36) ? Wp : Wv;
        float* dst = (e2 < 36) ? wpT : wvT;
        int tile = e2 % 36;
        int r0 = (tile / 6) * 64, c0 = (tile % 6) * 64;
        if (t < 256) {
#pragma unroll
            for (int rep = 0; rep < 16; ++rep) {
                int idx = rep * 256 + t;
                int r = idx >> 6, c = idx & 63;
                trt[r][c] = src[(size_t)(r0 + r) * C_ + c0 + c];
            }
        }
        __syncthreads();
        if (t < 256) {
#pragma unroll
            for (int rep = 0; rep < 16; ++rep) {
                int idx = rep * 256 + t;
                int rT = idx >> 6, cT = idx & 63;
                dst[(size_t)(c0 + rT) * C_ + r0 + cT] = trt[cT][rT];
            }
        }
        return;
    }
    // ---- qk part (r8 logic, unchanged) ----
    int ng = e & 7;
    int h = (e >> 3) % H_;
    int b = e / (8 * H_);
    int n0 = ng * 8;
#pragma unroll
    for (int i = 0; i < 8; ++i)
        qstage[i][t] = query[((size_t)(b * N_ + n0 + i)) * C_ + t];
    __syncthreads();
    if (t < 256) {
        int i0 = t >> 6, d = t & 63;
        const float4* wq = (const float4*)(Wq + (size_t)(h * DH_ + d) * C_);
        float accA = 0.f, accB = 0.f;
#pragma unroll 4
        for (int c4 = 0; c4 < C_ / 4; ++c4) {
            float4 w = wq[c4];
            float4 qa = *(const float4*)&qstage[i0][c4 * 4];
            float4 qb = *(const float4*)&qstage[i0 + 4][c4 * 4];
            accA += qa.x * w.x + qa.y * w.y + qa.z * w.z + qa.w * w.w;
            accB += qb.x * w.x + qb.y * w.y + qb.z * w.z + qb.w * w.w;
        }
        qv[i0][d] = accA * SCALE_;
        qv[i0 + 4][d] = accB * SCALE_;
    }
    __syncthreads();
    float a[8];
#pragma unroll
    for (int i = 0; i < 8; ++i) a[i] = 0.f;
    {
        const float* wk = Wk + (size_t)h * DH_ * C_ + t;
#pragma unroll 4
        for (int d = 0; d < DH_; ++d) {
            float w = wk[(size_t)d * C_];
#pragma unroll
            for (int i = 0; i < 8; ++i) a[i] += qv[i][d] * w;
        }
    }
#pragma unroll
    for (int i = 0; i < 8; ++i) qstage[i][t] = a[i];
    __syncthreads();
    {
        int r = t / 48, c0 = (t % 48) * 8;
        float v[8];
#pragma unroll
        for (int j = 0; j < 8; ++j) v[j] = qstage[r][c0 + j];
        unsigned short hi[8], lo[8];
#pragma unroll
        for (int j = 0; j < 8; ++j) {
            hi[j] = f2bf(v[j]);
            lo[j] = f2bf(v[j] - bf2f(hi[j]));
        }
        size_t o = ((size_t)(b * H_ + h) * N_ + n0 + r) * C_ + c0;
        float4 f0 = { v[0], v[1], v[2], v[3] };
        float4 f1 = { v[4], v[5], v[6], v[7] };
        *(float4*)(qk + o) = f0;
        *(float4*)(qk + o + 4) = f1;
        *(bf16x8*)(qkhi + o) = *(bf16x8*)hi;
        *(bf16x8*)(qklo + o) = *(bf16x8*)lo;
    }
}

// ---------------------------------------------------------------------------
// K2: logits via 3-pass bf16 MFMA + argmax. 64n x 128 tokens per block.
// (round-3 state, known-good)
// ---------------------------------------------------------------------------
__global__ __launch_bounds__(256) void attn_kernel(const unsigned short* __restrict__ qkhi,
                                                   const unsigned short* __restrict__ qklo,
                                                   const unsigned short* __restrict__ khi,
                                                   const unsigned short* __restrict__ klo,
                                                   unsigned int* __restrict__ idx,
                                                   unsigned int* __restrict__ flag_cnt,
                                                   unsigned int* __restrict__ flag_list) {
    __shared__ __align__(16) unsigned short sAhi[64 * 32];
    __shared__ __align__(16) unsigned short sAlo[64 * 32];
    __shared__ __align__(16) unsigned short sBhi[128 * 32];
    __shared__ __align__(16) unsigned short sBlo[128 * 32];
    int tid = threadIdx.x;
    int w = tid >> 6, l = tid & 63;
    int wm = w >> 1, wn = w & 1;
    int q4 = l >> 4, lm = l & 15;
    int s0 = blockIdx.x * 128;
    int h = blockIdx.y, b = blockIdx.z;
    size_t kbK = ((size_t)b * S_ + s0) * C_;
    size_t kbA = (size_t)(b * H_ + h) * N_ * C_;
    int trow16 = l >> 2;
    int tquart = ((l & 3) ^ ((l >> 3) & 3)) * 8;
    int sw = (q4 ^ ((lm >> 1) & 3)) * 8;

    f32x4 acc[2][4];
#pragma unroll
    for (int tm = 0; tm < 2; ++tm)
#pragma unroll
        for (int nt = 0; nt < 4; ++nt) acc[tm][nt] = (f32x4)0.f;

    for (int kc = 0; kc < C_; kc += 32) {
        __syncthreads();
#pragma unroll
        for (int i = 0; i < 6; ++i) {
            int gid = w * 6 + i;
            if (gid < 8) {
                gl_lds16(khi + kbK + (size_t)(gid * 16 + trow16) * C_ + kc + tquart,
                         (char*)sBhi + gid * 1024);
            } else if (gid < 16) {
                int g2 = gid - 8;
                gl_lds16(klo + kbK + (size_t)(g2 * 16 + trow16) * C_ + kc + tquart,
                         (char*)sBlo + g2 * 1024);
            } else if (gid < 20) {
                int g2 = gid - 16;
                gl_lds16(qkhi + kbA + (size_t)(g2 * 16 + trow16) * C_ + kc + tquart,
                         (char*)sAhi + g2 * 1024);
            } else {
                int g2 = gid - 20;
                gl_lds16(qklo + kbA + (size_t)(g2 * 16 + trow16) * C_ + kc + tquart,
                         (char*)sAlo + g2 * 1024);
            }
        }
        __syncthreads();
        bf16x8 ah[2], al[2];
#pragma unroll
        for (int tm = 0; tm < 2; ++tm) {
            int ar = (wm * 32 + tm * 16 + lm) * 32 + sw;
            ah[tm] = *(const bf16x8*)&sAhi[ar];
            al[tm] = *(const bf16x8*)&sAlo[ar];
        }
#pragma unroll
        for (int nt = 0; nt < 4; ++nt) {
            int nr = ((wn * 4 + nt) * 16 + lm) * 32 + sw;
            bf16x8 bh = *(const bf16x8*)&sBhi[nr];
            bf16x8 bl = *(const bf16x8*)&sBlo[nr];
#pragma unroll
            for (int tm = 0; tm < 2; ++tm) {
                acc[tm][nt] = __builtin_amdgcn_mfma_f32_16x16x32_bf16(ah[tm], bh, acc[tm][nt], 0, 0, 0);
                acc[tm][nt] = __builtin_amdgcn_mfma_f32_16x16x32_bf16(ah[tm], bl, acc[tm][nt], 0, 0, 0);
                acc[tm][nt] = __builtin_amdgcn_mfma_f32_16x16x32_bf16(al[tm], bh, acc[tm][nt], 0, 0, 0);
            }
        }
    }
    __syncthreads();

    float* rm1 = (float*)sBhi;
    float* rm2 = rm1 + 256;
    int* ri1 = (int*)(rm2 + 256);
    int* ri2 = ri1 + 256;

#pragma unroll
    for (int nt = 0; nt < 4; ++nt) {
        float m1 = -3.4e38f, m2 = -3.4e38f; int i1 = 0, i2 = 0;
#pragma unroll
        for (int tm = 0; tm < 2; ++tm)
#pragma unroll
            for (int r = 0; r < 4; ++r) {
                float v = acc[tm][nt][r];
                int row = wm * 32 + tm * 16 + q4 * 4 + r;
                if (v > m1) { m2 = m1; i2 = i1; m1 = v; i1 = row; }
                else if (v > m2) { m2 = v; i2 = row; }
            }
#pragma unroll
        for (int off = 16; off < 64; off <<= 1) {
            float om1 = __shfl_xor(m1, off), om2 = __shfl_xor(m2, off);
            int oi1 = __shfl_xor(i1, off), oi2 = __shfl_xor(i2, off);
            bool take = (om1 > m1) || (om1 == m1 && oi1 < i1);
            float w1 = take ? om1 : m1; int wi1 = take ? oi1 : i1;
            float l1 = take ? m1 : om1; int li1 = take ? i1 : oi1;
            float s2 = m2; int si2 = i2;
            if (om2 > s2) { s2 = om2; si2 = oi2; }
            if (l1 > s2) { s2 = l1; si2 = li1; }
            m1 = w1; i1 = wi1; m2 = s2; i2 = si2;
        }
        if (q4 == 0) {
            int cw = (wn * 4 + nt) * 16 + lm;
            rm1[wm * 128 + cw] = m1; rm2[wm * 128 + cw] = m2;
            ri1[wm * 128 + cw] = i1; ri2[wm * 128 + cw] = i2;
        }
    }
    __syncthreads();
    if (tid < 128) {
        float a1 = rm1[tid], a2 = rm2[tid];
        int ai1 = ri1[tid], ai2 = ri2[tid];
        float b1 = rm1[128 + tid], b2 = rm2[128 + tid];
        int bi1 = ri1[128 + tid], bi2 = ri2[128 + tid];
        float w1, s2; int wi1, wi2;
        if (b1 > a1) { w1 = b1; wi1 = bi1; s2 = a1; wi2 = ai1; if (b2 > s2) { s2 = b2; wi2 = bi2; } }
        else         { w1 = a1; wi1 = ai1; s2 = a2; wi2 = ai2; if (b1 > s2) { s2 = b1; wi2 = bi1; } }
        idx[(size_t)(b * H_ + h) * S_ + s0 + tid] = (unsigned)wi1;
        if (w1 - s2 < TAU_) {
            unsigned p = atomicAdd(flag_cnt, 1u);
            if (p < LISTCAP) {
                unsigned tok = (unsigned)((b * H_ + h) * S_ + s0 + tid);
                flag_list[p] = tok | ((unsigned)wi1 << 19) | ((unsigned)wi2 << 25);
            }
        }
    }
}

// ---------------------------------------------------------------------------
// K3: fixup — exact fp32 recompute of two candidate rows for near-ties
// ---------------------------------------------------------------------------
__global__ __launch_bounds__(256) void fixup_kernel(const float* __restrict__ qk,
                                                    const float* __restrict__ key,
                                                    const unsigned int* __restrict__ flag_list,
                                                    const unsigned int* __restrict__ flag_cnt,
                                                    unsigned int* __restrict__ idx) {
    int w = threadIdx.x >> 6, l = threadIdx.x & 63;
    unsigned total = flag_cnt[0];
    if (total > LISTCAP) total = LISTCAP;
    for (unsigned t = blockIdx.x * 4 + w; t < total; t += gridDim.x * 4) {
        unsigned e = flag_list[t];
        unsigned tok = e & 0x7FFFFu;
        int i1 = (int)((e >> 19) & 63u), i2 = (int)((e >> 25) & 63u);
        unsigned bh = tok >> 12;
        unsigned s = tok & 4095u;
        unsigned bb = bh / H_;
        int l32 = l & 31;
        const float* qrow = qk + ((size_t)bh * N_ + (l < 32 ? i1 : i2)) * C_ + l32 * 12;
        const float* krow = key + ((size_t)bb * S_ + s) * C_ + l32 * 12;
        float sum = 0.f;
#pragma unroll
        for (int c = 0; c < 12; ++c) sum += qrow[c] * krow[c];
#pragma unroll
        for (int off = 1; off < 32; off <<= 1) sum += __shfl_xor(sum, off);
        float d1 = __shfl(sum, 0);
        float d2 = __shfl(sum, 32);
        int win = (d2 > d1 || (d2 == d1 && i2 < i1)) ? i2 : i1;
        if (l == 0) idx[(size_t)bh * S_ + s] = (unsigned)win;
    }
}

// ---------------------------------------------------------------------------
// K4: hist_build — per (b,h): histogram -> scan -> counting-sort placement
// ---------------------------------------------------------------------------
__global__ __launch_bounds__(256) void hist_build_kernel(const unsigned int* __restrict__ idx,
                                                         unsigned int* __restrict__ offs,
                                                         unsigned int* __restrict__ order) {
    __shared__ unsigned int cnts[N_];
    __shared__ unsigned int pos[N_];
    int tid = threadIdx.x;
    int bh = blockIdx.x;
    if (tid < N_) cnts[tid] = 0u;
    __syncthreads();
    const unsigned int* idxp = idx + (size_t)bh * S_;
    for (int s = tid; s < S_; s += 256) atomicAdd(&cnts[idxp[s]], 1u);
    __syncthreads();
    if (tid < N_) {
        unsigned v = cnts[tid];
        unsigned x = v;
#pragma unroll
        for (int off = 1; off < 64; off <<= 1) {
            unsigned y = __shfl_up(x, off);
            if (tid >= off) x += y;
        }
        unsigned excl = x - v;
        pos[tid] = excl;
        offs[(size_t)bh * 65 + tid] = excl;
        if (tid == 63) offs[(size_t)bh * 65 + 64] = x;   // == S_
    }
    __syncthreads();
    unsigned int* op = order + (size_t)bh * S_;
    for (int s = tid; s < S_; s += 256) {
        unsigned g = idxp[s];
        unsigned p = atomicAdd(&pos[g], 1u);
        op[p] = (unsigned)s;
    }
}

// ---------------------------------------------------------------------------
// K5+K6 fused: aggv — gather phase = r8 (8 parts, 8-wide batching, known
// -good). ROUND-THIS phase B: was 1 wave serial row-strided Wv dot with 7
// waves idle. Now: (1) zrow precompute (384 threads, 8 LDS broadcast adds),
// (2) 8-wave c-range-split partial dots reading WvT COALESCED (4B/lane
// consecutive), (3) wave-0 combine. Linear post-argmax path — regrouping
// only (no discrete risk).
// ---------------------------------------------------------------------------
#define AGG_PARTS 8
__global__ __launch_bounds__(512) void aggv_kernel(const unsigned short* __restrict__ khi,
                                                   const unsigned int* __restrict__ order,
                                                   const unsigned int* __restrict__ offs,
                                                   const float* __restrict__ wvT,
                                                   float* __restrict__ gvn) {
    __shared__ float lrows[AGG_PARTS][C_];
    __shared__ float zrow[C_];
    __shared__ float pacc[AGG_PARTS][DH_];
    int tid = threadIdx.x;
    int part = tid >> 6, l = tid & 63;
    int h = blockIdx.y, b = blockIdx.z;
    int bh = b * H_ + h;
    int g = blockIdx.x;
    unsigned beg = offs[(size_t)bh * 65 + g];
    unsigned end = offs[(size_t)bh * 65 + g + 1];
    int cnt = (int)(end - beg);
    float inv = 1.f / ((float)cnt + 1.f);
    const unsigned int* op = order + (size_t)bh * S_ + beg;
    const unsigned int* kbase = (const unsigned int*)(khi + (size_t)b * S_ * C_);
    float a0 = 0.f, a1 = 0.f, a2 = 0.f, a3 = 0.f, a4 = 0.f, a5 = 0.f;
    for (int base = part * 64; base < cnt; base += 64 * AGG_PARTS) {
        int m = cnt - base; if (m > 64) m = 64;
        unsigned sv = (l < m) ? op[base + l] : 0u;
        int i = 0;
        for (; i + 8 <= m; i += 8) {
            int ss[8];
#pragma unroll
            for (int j = 0; j < 8; ++j) ss[j] = __shfl((int)sv, i + j);
            unsigned u[8][3];
#pragma unroll
            for (int j = 0; j < 8; ++j) {
                const unsigned int* kp = kbase + (size_t)ss[j] * (C_ / 2) + l * 3;
                u[j][0] = kp[0]; u[j][1] = kp[1]; u[j][2] = kp[2];
            }
#pragma unroll
            for (int j = 0; j < 8; ++j) {
                a0 += bfu_lo(u[j][0]); a1 += bfu_hi(u[j][0]);
                a2 += bfu_lo(u[j][1]); a3 += bfu_hi(u[j][1]);
                a4 += bfu_lo(u[j][2]); a5 += bfu_hi(u[j][2]);
            }
        }
        for (; i < m; ++i) {
            int s = (int)__shfl((int)sv, i);
            const unsigned int* kp = kbase + (size_t)s * (C_ / 2) + l * 3;
            unsigned u0 = kp[0], u1 = kp[1], u2 = kp[2];
            a0 += bfu_lo(u0); a1 += bfu_hi(u0);
            a2 += bfu_lo(u1); a3 += bfu_hi(u1);
            a4 += bfu_lo(u2); a5 += bfu_hi(u2);
        }
    }
    float* lp = &lrows[part][l * 6];
    lp[0] = a0 * inv; lp[1] = a1 * inv; lp[2] = a2 * inv;
    lp[3] = a3 * inv; lp[4] = a4 * inv; lp[5] = a5 * inv;
    __syncthreads();
    // zrow[c] = sum over parts (sequential order, matches old z semantics)
    if (tid < C_) {
        float z = lrows[0][tid];
#pragma unroll
        for (int p = 1; p < AGG_PARTS; ++p) z += lrows[p][tid];
        zrow[tid] = z;
    }
    __syncthreads();
    // wave-split partial dot: wave `part` covers c in [part*48, part*48+48)
    {
        float a = 0.f;
        int cb = part * (C_ / AGG_PARTS);
#pragma unroll 8
        for (int cc = 0; cc < C_ / AGG_PARTS; ++cc) {
            int c = cb + cc;
            a += zrow[c] * wvT[(size_t)c * C_ + h * DH_ + l];
        }
        pacc[part][l] = a;
    }
    __syncthreads();
    if (part == 0) {
        float acc = pacc[0][l];
#pragma unroll
        for (int p = 1; p < AGG_PARTS; ++p) acc += pacc[p][l];
        gvn[((size_t)bh * N_ + g) * DH_ + l] = acc;
    }
}

// ---------------------------------------------------------------------------
// K7: out — ROUND-THIS: 1024 blocks (1 token each, 4x parallelism) + WpT
// coalesced reads (was row-per-thread stride-1536B at 1 block/CU).
// Linear post-argmax path — regrouping only.
// ---------------------------------------------------------------------------
__global__ __launch_bounds__(384) void out_kernel(const float* __restrict__ gvn,
                                                  const float* __restrict__ wpT,
                                                  const float* __restrict__ bp,
                                                  float* __restrict__ out) {
    __shared__ float vals[C_];
    int bn = blockIdx.x;                  // 0..1023
    int b = bn >> 6, n = bn & 63;
    int t = threadIdx.x;
    int h = t >> 6, d = t & 63;
    vals[t] = gvn[((size_t)(b * H_ + h) * N_ + n) * DH_ + d];
    __syncthreads();
    float s = bp[t];
#pragma unroll 8
    for (int c = 0; c < C_; ++c)
        s += vals[c] * wpT[(size_t)c * C_ + t];
    out[(size_t)bn * C_ + t] = s;
}

// ---------------------------------------------------------------------------
extern "C" void kernel_launch(void* const* d_in, const int* in_sizes, int n_in,
                              void* d_out, int out_size, void* d_ws, size_t ws_size,
                              hipStream_t stream) {
    (void)in_sizes; (void)n_in; (void)out_size; (void)ws_size;
    const float* query = (const float*)d_in[0];
    const float* key   = (const float*)d_in[1];
    const float* Wq    = (const float*)d_in[2];
    const float* Wk    = (const float*)d_in[3];
    const float* Wv    = (const float*)d_in[4];
    const float* Wp    = (const float*)d_in[5];
    const float* bp    = (const float*)d_in[6];
    float* out = (float*)d_out;

    char* ws = (char*)d_ws;
    size_t off = 0;
    unsigned short* khi  = (unsigned short*)(ws + off); off += (size_t)B_ * S_ * C_ * 2;
    unsigned short* klo  = (unsigned short*)(ws + off); off += (size_t)B_ * S_ * C_ * 2;
    float* qk            = (float*)(ws + off);          off += (size_t)B_ * H_ * N_ * C_ * 4;
    unsigned short* qkhi = (unsigned short*)(ws + off); off += (size_t)B_ * H_ * N_ * C_ * 2;
    unsigned short* qklo = (unsigned short*)(ws + off); off += (size_t)B_ * H_ * N_ * C_ * 2;
    unsigned int* idx    = (unsigned int*)(ws + off);   off += (size_t)B_ * H_ * S_ * 4;
    unsigned int* order  = (unsigned int*)(ws + off);   off += (size_t)B_ * H_ * S_ * 4;
    unsigned int* offs   = (unsigned int*)(ws + off);   off += (size_t)B_ * H_ * 65 * 4;
    float* gvn           = (float*)(ws + off);          off += (size_t)B_ * H_ * N_ * DH_ * 4;
    float* wpT           = (float*)(ws + off);          off += (size_t)C_ * C_ * 4;
    float* wvT           = (float*)(ws + off);          off += (size_t)C_ * C_ * 4;
    unsigned int* fcnt   = (unsigned int*)(ws + off);   off += 256;
    unsigned int* flist  = (unsigned int*)(ws + off);   off += (size_t)LISTCAP * 4;

    hipMemsetAsync(fcnt, 0, 256, stream);

    prepqk_kernel<<<PREP_BLOCKS + QK_BLOCKS + TR_BLOCKS, 384, 0, stream>>>(
        key, khi, klo, query, Wq, Wk, qk, qkhi, qklo, Wp, Wv, wpT, wvT);
    attn_kernel<<<dim3(S_ / 128, H_, B_), 256, 0, stream>>>(qkhi, qklo, khi, klo, idx, fcnt, flist);
    fixup_kernel<<<256, 256, 0, stream>>>(qk, key, flist, fcnt, idx);
    hist_build_kernel<<<B_ * H_, 256, 0, stream>>>(idx, offs, order);
    aggv_kernel<<<dim3(N_, H_, B_), 512, 0, stream>>>(khi, order, offs, wvT, gvn);
    out_kernel<<<B_ * N_, 384, 0, stream>>>(gvn, wpT, bp, out);
}

// Round 10
// 377.737 us; speedup vs baseline: 1.4232x; 1.0650x over previous
//
#include <hip/hip_runtime.h>
#include <hip/hip_bf16.h>
#include <stdint.h>

#define B_ 16
#define N_ 64
#define S_ 4096
#define C_ 384
#define H_ 6
#define DH_ 64
#define SCALE_ 0.125f
#define TAU_ 2e-4f
#define LISTCAP 262144

typedef __attribute__((ext_vector_type(8))) short bf16x8;
typedef __attribute__((ext_vector_type(4))) float f32x4;
typedef __attribute__((ext_vector_type(4))) unsigned short u16x4;

static __device__ __forceinline__ unsigned short f2bf(float x) {
    union { float f; unsigned u; } v; v.f = x;
    unsigned r = v.u + 0x7FFFu + ((v.u >> 16) & 1u);
    return (unsigned short)(r >> 16);
}
static __device__ __forceinline__ float bf2f(unsigned short b) {
    union { unsigned u; float f; } v; v.u = ((unsigned)b) << 16; return v.f;
}
static __device__ __forceinline__ float bfu_lo(unsigned u) {
    union { unsigned u; float f; } v; v.u = u << 16; return v.f;
}
static __device__ __forceinline__ float bfu_hi(unsigned u) {
    union { unsigned u; float f; } v; v.u = u & 0xFFFF0000u; return v.f;
}

// async global->LDS, 16B/lane; LDS dest = wave-uniform base + lane*16
static __device__ __forceinline__ void gl_lds16(const void* g, void* l) {
    __builtin_amdgcn_global_load_lds(
        (const __attribute__((address_space(1))) unsigned int*)g,
        (__attribute__((address_space(3))) unsigned int*)l, 16, 0, 0);
}

// ---------------------------------------------------------------------------
// K0+K1 fused: prep + qk + Wp/Wv transpose tiles.
// ROUND-THIS: qk phase-1 was the ~90us invariant — each thread read a full
// Wq ROW (lane d -> row h*64+d), so every float4 load touched 64 distinct
// cache lines (stride 1536B): ~19M line-transactions, texture-unit-rate
// limited (duration invariant to occupancy r3/r4/r6/r9). Fix: stage Wq
// through LDS in 48-col chunks loaded COALESCED by all 384 threads, then
// FMA from LDS (WQS padded [64][49] -> d/d+32 2-way bank alias = free).
// Per-(i,d) summation keeps the exact old 4-term-group expression tree,
// sequential c -> qv/qk bit-identical. sbuf unioned with transpose tile:
// LDS unchanged (~31KB). prep/transpose parts unchanged from r9.
// ---------------------------------------------------------------------------
#define PREP_BLOCKS 8192   // 8192 * 3072 elems = 16*4096*384
#define QK_BLOCKS   (8 * H_ * B_)   // 768
#define TR_BLOCKS   72              // 2 matrices x 36 (64x64) tiles

#define TRT(r, c) sbuf[(r) * 65 + (c)]
#define WQS(d, c) sbuf[(d) * 49 + (c)]

__global__ __launch_bounds__(384) void prepqk_kernel(const float* __restrict__ key,
                                                     unsigned short* __restrict__ khi,
                                                     unsigned short* __restrict__ klo,
                                                     const float* __restrict__ query,
                                                     const float* __restrict__ Wq,
                                                     const float* __restrict__ Wk,
                                                     float* __restrict__ qk,
                                                     unsigned short* __restrict__ qkhi,
                                                     unsigned short* __restrict__ qklo,
                                                     const float* __restrict__ Wp,
                                                     const float* __restrict__ Wv,
                                                     float* __restrict__ wpT,
                                                     float* __restrict__ wvT) {
    __shared__ float qstage[8][C_];   // qk: staged query rows / output transpose buffer
    __shared__ float qv[8][DH_];
    __shared__ float sbuf[64 * 65];   // transpose tile (TRT) / Wq chunk stage (WQS)
    int t = threadIdx.x;
    if (blockIdx.x < PREP_BLOCKS) {
        size_t blk = (size_t)blockIdx.x * 3072;
#pragma unroll
        for (int half = 0; half < 2; ++half) {
            size_t base = blk + (size_t)half * 1536 + (size_t)t * 4;
            float4 x = *(const float4*)(key + base);
            float xs[4] = { x.x, x.y, x.z, x.w };
            unsigned short hi[4], lo[4];
#pragma unroll
            for (int i = 0; i < 4; ++i) {
                hi[i] = f2bf(xs[i]);
                lo[i] = f2bf(xs[i] - bf2f(hi[i]));
            }
            *(u16x4*)(khi + base) = *(u16x4*)hi;
            *(u16x4*)(klo + base) = *(u16x4*)lo;
        }
        return;
    }
    int e = blockIdx.x - PREP_BLOCKS;
    if (e >= QK_BLOCKS) {
        // ---- transpose part: WpT[c][j] = Wp[j][c], WvT likewise ----
        int e2 = e - QK_BLOCKS;                 // 0..71
        const float* src = (e2 < 36) ? Wp : Wv;
        float* dst = (e2 < 36) ? wpT : wvT;
        int tile = e2 % 36;
        int r0 = (tile / 6) * 64, c0 = (tile % 6) * 64;
        if (t < 256) {
#pragma unroll
            for (int rep = 0; rep < 16; ++rep) {
                int idx = rep * 256 + t;
                int r = idx >> 6, c = idx & 63;
                TRT(r, c) = src[(size_t)(r0 + r) * C_ + c0 + c];
            }
        }
        __syncthreads();
        if (t < 256) {
#pragma unroll
            for (int rep = 0; rep < 16; ++rep) {
                int idx = rep * 256 + t;
                int rT = idx >> 6, cT = idx & 63;
                dst[(size_t)(c0 + rT) * C_ + r0 + cT] = TRT(cT, rT);
            }
        }
        return;
    }
    // ---- qk part ----
    int ng = e & 7;
    int h = (e >> 3) % H_;
    int b = e / (8 * H_);
    int n0 = ng * 8;
#pragma unroll
    for (int i = 0; i < 8; ++i)
        qstage[i][t] = query[((size_t)(b * N_ + n0 + i)) * C_ + t];
    // phase 1: q-projection with LDS-staged Wq chunks (coalesced global
    // reads). Per-(i,d) accumulation: 4-term groups, sequential c — the
    // exact expression tree of the old float4-row version -> qv bit-identical.
    {
        int i0 = (t < 256) ? (t >> 6) : 0;
        int d = t & 63;
        float accA = 0.f, accB = 0.f;
        for (int c0 = 0; c0 < C_; c0 += 48) {
            __syncthreads();   // qstage ready (first iter) / prev chunk consumed
#pragma unroll
            for (int rep = 0; rep < 8; ++rep) {
                int idx2 = rep * 384 + t;
                int r = idx2 / 48, c = idx2 % 48;
                WQS(r, c) = Wq[(size_t)(h * DH_ + r) * C_ + c0 + c];
            }
            __syncthreads();
            if (t < 256) {
#pragma unroll
                for (int cc = 0; cc < 48; cc += 4) {
                    accA += qstage[i0][c0 + cc + 0] * WQS(d, cc + 0)
                          + qstage[i0][c0 + cc + 1] * WQS(d, cc + 1)
                          + qstage[i0][c0 + cc + 2] * WQS(d, cc + 2)
                          + qstage[i0][c0 + cc + 3] * WQS(d, cc + 3);
                    accB += qstage[i0 + 4][c0 + cc + 0] * WQS(d, cc + 0)
                          + qstage[i0 + 4][c0 + cc + 1] * WQS(d, cc + 1)
                          + qstage[i0 + 4][c0 + cc + 2] * WQS(d, cc + 2)
                          + qstage[i0 + 4][c0 + cc + 3] * WQS(d, cc + 3);
                }
            }
        }
        if (t < 256) {
            qv[i0][d] = accA * SCALE_;
            qv[i0 + 4][d] = accB * SCALE_;
        }
    }
    __syncthreads();
    // phase 2a: qk[n,t] = sum_d qv[n][d] * Wk[h*64+d][t] (coalesced in t)
    float a[8];
#pragma unroll
    for (int i = 0; i < 8; ++i) a[i] = 0.f;
    {
        const float* wk = Wk + (size_t)h * DH_ * C_ + t;
#pragma unroll 4
        for (int d = 0; d < DH_; ++d) {
            float w = wk[(size_t)d * C_];
#pragma unroll
            for (int i = 0; i < 8; ++i) a[i] += qv[i][d] * w;
        }
    }
    // phase 2b: LDS transpose -> vector stores
#pragma unroll
    for (int i = 0; i < 8; ++i) qstage[i][t] = a[i];
    __syncthreads();
    {
        int r = t / 48, c0 = (t % 48) * 8;
        float v[8];
#pragma unroll
        for (int j = 0; j < 8; ++j) v[j] = qstage[r][c0 + j];
        unsigned short hi[8], lo[8];
#pragma unroll
        for (int j = 0; j < 8; ++j) {
            hi[j] = f2bf(v[j]);
            lo[j] = f2bf(v[j] - bf2f(hi[j]));
        }
        size_t o = ((size_t)(b * H_ + h) * N_ + n0 + r) * C_ + c0;
        float4 f0 = { v[0], v[1], v[2], v[3] };
        float4 f1 = { v[4], v[5], v[6], v[7] };
        *(float4*)(qk + o) = f0;
        *(float4*)(qk + o + 4) = f1;
        *(bf16x8*)(qkhi + o) = *(bf16x8*)hi;
        *(bf16x8*)(qklo + o) = *(bf16x8*)lo;
    }
}

// ---------------------------------------------------------------------------
// K2: logits via 3-pass bf16 MFMA + argmax. 64n x 128 tokens per block.
// (round-3 state, known-good)
// ---------------------------------------------------------------------------
__global__ __launch_bounds__(256) void attn_kernel(const unsigned short* __restrict__ qkhi,
                                                   const unsigned short* __restrict__ qklo,
                                                   const unsigned short* __restrict__ khi,
                                                   const unsigned short* __restrict__ klo,
                                                   unsigned int* __restrict__ idx,
                                                   unsigned int* __restrict__ flag_cnt,
                                                   unsigned int* __restrict__ flag_list) {
    __shared__ __align__(16) unsigned short sAhi[64 * 32];
    __shared__ __align__(16) unsigned short sAlo[64 * 32];
    __shared__ __align__(16) unsigned short sBhi[128 * 32];
    __shared__ __align__(16) unsigned short sBlo[128 * 32];
    int tid = threadIdx.x;
    int w = tid >> 6, l = tid & 63;
    int wm = w >> 1, wn = w & 1;
    int q4 = l >> 4, lm = l & 15;
    int s0 = blockIdx.x * 128;
    int h = blockIdx.y, b = blockIdx.z;
    size_t kbK = ((size_t)b * S_ + s0) * C_;
    size_t kbA = (size_t)(b * H_ + h) * N_ * C_;
    int trow16 = l >> 2;
    int tquart = ((l & 3) ^ ((l >> 3) & 3)) * 8;
    int sw = (q4 ^ ((lm >> 1) & 3)) * 8;

    f32x4 acc[2][4];
#pragma unroll
    for (int tm = 0; tm < 2; ++tm)
#pragma unroll
        for (int nt = 0; nt < 4; ++nt) acc[tm][nt] = (f32x4)0.f;

    for (int kc = 0; kc < C_; kc += 32) {
        __syncthreads();
#pragma unroll
        for (int i = 0; i < 6; ++i) {
            int gid = w * 6 + i;
            if (gid < 8) {
                gl_lds16(khi + kbK + (size_t)(gid * 16 + trow16) * C_ + kc + tquart,
                         (char*)sBhi + gid * 1024);
            } else if (gid < 16) {
                int g2 = gid - 8;
                gl_lds16(klo + kbK + (size_t)(g2 * 16 + trow16) * C_ + kc + tquart,
                         (char*)sBlo + g2 * 1024);
            } else if (gid < 20) {
                int g2 = gid - 16;
                gl_lds16(qkhi + kbA + (size_t)(g2 * 16 + trow16) * C_ + kc + tquart,
                         (char*)sAhi + g2 * 1024);
            } else {
                int g2 = gid - 20;
                gl_lds16(qklo + kbA + (size_t)(g2 * 16 + trow16) * C_ + kc + tquart,
                         (char*)sAlo + g2 * 1024);
            }
        }
        __syncthreads();
        bf16x8 ah[2], al[2];
#pragma unroll
        for (int tm = 0; tm < 2; ++tm) {
            int ar = (wm * 32 + tm * 16 + lm) * 32 + sw;
            ah[tm] = *(const bf16x8*)&sAhi[ar];
            al[tm] = *(const bf16x8*)&sAlo[ar];
        }
#pragma unroll
        for (int nt = 0; nt < 4; ++nt) {
            int nr = ((wn * 4 + nt) * 16 + lm) * 32 + sw;
            bf16x8 bh = *(const bf16x8*)&sBhi[nr];
            bf16x8 bl = *(const bf16x8*)&sBlo[nr];
#pragma unroll
            for (int tm = 0; tm < 2; ++tm) {
                acc[tm][nt] = __builtin_amdgcn_mfma_f32_16x16x32_bf16(ah[tm], bh, acc[tm][nt], 0, 0, 0);
                acc[tm][nt] = __builtin_amdgcn_mfma_f32_16x16x32_bf16(ah[tm], bl, acc[tm][nt], 0, 0, 0);
                acc[tm][nt] = __builtin_amdgcn_mfma_f32_16x16x32_bf16(al[tm], bh, acc[tm][nt], 0, 0, 0);
            }
        }
    }
    __syncthreads();

    float* rm1 = (float*)sBhi;
    float* rm2 = rm1 + 256;
    int* ri1 = (int*)(rm2 + 256);
    int* ri2 = ri1 + 256;

#pragma unroll
    for (int nt = 0; nt < 4; ++nt) {
        float m1 = -3.4e38f, m2 = -3.4e38f; int i1 = 0, i2 = 0;
#pragma unroll
        for (int tm = 0; tm < 2; ++tm)
#pragma unroll
            for (int r = 0; r < 4; ++r) {
                float v = acc[tm][nt][r];
                int row = wm * 32 + tm * 16 + q4 * 4 + r;
                if (v > m1) { m2 = m1; i2 = i1; m1 = v; i1 = row; }
                else if (v > m2) { m2 = v; i2 = row; }
            }
#pragma unroll
        for (int off = 16; off < 64; off <<= 1) {
            float om1 = __shfl_xor(m1, off), om2 = __shfl_xor(m2, off);
            int oi1 = __shfl_xor(i1, off), oi2 = __shfl_xor(i2, off);
            bool take = (om1 > m1) || (om1 == m1 && oi1 < i1);
            float w1 = take ? om1 : m1; int wi1 = take ? oi1 : i1;
            float l1 = take ? m1 : om1; int li1 = take ? i1 : oi1;
            float s2 = m2; int si2 = i2;
            if (om2 > s2) { s2 = om2; si2 = oi2; }
            if (l1 > s2) { s2 = l1; si2 = li1; }
            m1 = w1; i1 = wi1; m2 = s2; i2 = si2;
        }
        if (q4 == 0) {
            int cw = (wn * 4 + nt) * 16 + lm;
            rm1[wm * 128 + cw] = m1; rm2[wm * 128 + cw] = m2;
            ri1[wm * 128 + cw] = i1; ri2[wm * 128 + cw] = i2;
        }
    }
    __syncthreads();
    if (tid < 128) {
        float a1 = rm1[tid], a2 = rm2[tid];
        int ai1 = ri1[tid], ai2 = ri2[tid];
        float b1 = rm1[128 + tid], b2 = rm2[128 + tid];
        int bi1 = ri1[128 + tid], bi2 = ri2[128 + tid];
        float w1, s2; int wi1, wi2;
        if (b1 > a1) { w1 = b1; wi1 = bi1; s2 = a1; wi2 = ai1; if (b2 > s2) { s2 = b2; wi2 = bi2; } }
        else         { w1 = a1; wi1 = ai1; s2 = a2; wi2 = ai2; if (b1 > s2) { s2 = b1; wi2 = bi1; } }
        idx[(size_t)(b * H_ + h) * S_ + s0 + tid] = (unsigned)wi1;
        if (w1 - s2 < TAU_) {
            unsigned p = atomicAdd(flag_cnt, 1u);
            if (p < LISTCAP) {
                unsigned tok = (unsigned)((b * H_ + h) * S_ + s0 + tid);
                flag_list[p] = tok | ((unsigned)wi1 << 19) | ((unsigned)wi2 << 25);
            }
        }
    }
}

// ---------------------------------------------------------------------------
// K3: fixup — exact fp32 recompute of two candidate rows for near-ties
// ---------------------------------------------------------------------------
__global__ __launch_bounds__(256) void fixup_kernel(const float* __restrict__ qk,
                                                    const float* __restrict__ key,
                                                    const unsigned int* __restrict__ flag_list,
                                                    const unsigned int* __restrict__ flag_cnt,
                                                    unsigned int* __restrict__ idx) {
    int w = threadIdx.x >> 6, l = threadIdx.x & 63;
    unsigned total = flag_cnt[0];
    if (total > LISTCAP) total = LISTCAP;
    for (unsigned t = blockIdx.x * 4 + w; t < total; t += gridDim.x * 4) {
        unsigned e = flag_list[t];
        unsigned tok = e & 0x7FFFFu;
        int i1 = (int)((e >> 19) & 63u), i2 = (int)((e >> 25) & 63u);
        unsigned bh = tok >> 12;
        unsigned s = tok & 4095u;
        unsigned bb = bh / H_;
        int l32 = l & 31;
        const float* qrow = qk + ((size_t)bh * N_ + (l < 32 ? i1 : i2)) * C_ + l32 * 12;
        const float* krow = key + ((size_t)bb * S_ + s) * C_ + l32 * 12;
        float sum = 0.f;
#pragma unroll
        for (int c = 0; c < 12; ++c) sum += qrow[c] * krow[c];
#pragma unroll
        for (int off = 1; off < 32; off <<= 1) sum += __shfl_xor(sum, off);
        float d1 = __shfl(sum, 0);
        float d2 = __shfl(sum, 32);
        int win = (d2 > d1 || (d2 == d1 && i2 < i1)) ? i2 : i1;
        if (l == 0) idx[(size_t)bh * S_ + s] = (unsigned)win;
    }
}

// ---------------------------------------------------------------------------
// K4: hist_build — per (b,h): histogram -> scan -> counting-sort placement
// ---------------------------------------------------------------------------
__global__ __launch_bounds__(256) void hist_build_kernel(const unsigned int* __restrict__ idx,
                                                         unsigned int* __restrict__ offs,
                                                         unsigned int* __restrict__ order) {
    __shared__ unsigned int cnts[N_];
    __shared__ unsigned int pos[N_];
    int tid = threadIdx.x;
    int bh = blockIdx.x;
    if (tid < N_) cnts[tid] = 0u;
    __syncthreads();
    const unsigned int* idxp = idx + (size_t)bh * S_;
    for (int s = tid; s < S_; s += 256) atomicAdd(&cnts[idxp[s]], 1u);
    __syncthreads();
    if (tid < N_) {
        unsigned v = cnts[tid];
        unsigned x = v;
#pragma unroll
        for (int off = 1; off < 64; off <<= 1) {
            unsigned y = __shfl_up(x, off);
            if (tid >= off) x += y;
        }
        unsigned excl = x - v;
        pos[tid] = excl;
        offs[(size_t)bh * 65 + tid] = excl;
        if (tid == 63) offs[(size_t)bh * 65 + 64] = x;   // == S_
    }
    __syncthreads();
    unsigned int* op = order + (size_t)bh * S_;
    for (int s = tid; s < S_; s += 256) {
        unsigned g = idxp[s];
        unsigned p = atomicAdd(&pos[g], 1u);
        op[p] = (unsigned)s;
    }
}

// ---------------------------------------------------------------------------
// K5+K6 fused: aggv — 8-part skew-proof gather (r8) + coalesced WvT wave-
// split phase B (r9). Known-good.
// ---------------------------------------------------------------------------
#define AGG_PARTS 8
__global__ __launch_bounds__(512) void aggv_kernel(const unsigned short* __restrict__ khi,
                                                   const unsigned int* __restrict__ order,
                                                   const unsigned int* __restrict__ offs,
                                                   const float* __restrict__ wvT,
                                                   float* __restrict__ gvn) {
    __shared__ float lrows[AGG_PARTS][C_];
    __shared__ float zrow[C_];
    __shared__ float pacc[AGG_PARTS][DH_];
    int tid = threadIdx.x;
    int part = tid >> 6, l = tid & 63;
    int h = blockIdx.y, b = blockIdx.z;
    int bh = b * H_ + h;
    int g = blockIdx.x;
    unsigned beg = offs[(size_t)bh * 65 + g];
    unsigned end = offs[(size_t)bh * 65 + g + 1];
    int cnt = (int)(end - beg);
    float inv = 1.f / ((float)cnt + 1.f);
    const unsigned int* op = order + (size_t)bh * S_ + beg;
    const unsigned int* kbase = (const unsigned int*)(khi + (size_t)b * S_ * C_);
    float a0 = 0.f, a1 = 0.f, a2 = 0.f, a3 = 0.f, a4 = 0.f, a5 = 0.f;
    for (int base = part * 64; base < cnt; base += 64 * AGG_PARTS) {
        int m = cnt - base; if (m > 64) m = 64;
        unsigned sv = (l < m) ? op[base + l] : 0u;
        int i = 0;
        for (; i + 8 <= m; i += 8) {
            int ss[8];
#pragma unroll
            for (int j = 0; j < 8; ++j) ss[j] = __shfl((int)sv, i + j);
            unsigned u[8][3];
#pragma unroll
            for (int j = 0; j < 8; ++j) {
                const unsigned int* kp = kbase + (size_t)ss[j] * (C_ / 2) + l * 3;
                u[j][0] = kp[0]; u[j][1] = kp[1]; u[j][2] = kp[2];
            }
#pragma unroll
            for (int j = 0; j < 8; ++j) {
                a0 += bfu_lo(u[j][0]); a1 += bfu_hi(u[j][0]);
                a2 += bfu_lo(u[j][1]); a3 += bfu_hi(u[j][1]);
                a4 += bfu_lo(u[j][2]); a5 += bfu_hi(u[j][2]);
            }
        }
        for (; i < m; ++i) {
            int s = (int)__shfl((int)sv, i);
            const unsigned int* kp = kbase + (size_t)s * (C_ / 2) + l * 3;
            unsigned u0 = kp[0], u1 = kp[1], u2 = kp[2];
            a0 += bfu_lo(u0); a1 += bfu_hi(u0);
            a2 += bfu_lo(u1); a3 += bfu_hi(u1);
            a4 += bfu_lo(u2); a5 += bfu_hi(u2);
        }
    }
    float* lp = &lrows[part][l * 6];
    lp[0] = a0 * inv; lp[1] = a1 * inv; lp[2] = a2 * inv;
    lp[3] = a3 * inv; lp[4] = a4 * inv; lp[5] = a5 * inv;
    __syncthreads();
    if (tid < C_) {
        float z = lrows[0][tid];
#pragma unroll
        for (int p = 1; p < AGG_PARTS; ++p) z += lrows[p][tid];
        zrow[tid] = z;
    }
    __syncthreads();
    {
        float a = 0.f;
        int cb = part * (C_ / AGG_PARTS);
#pragma unroll 8
        for (int cc = 0; cc < C_ / AGG_PARTS; ++cc) {
            int c = cb + cc;
            a += zrow[c] * wvT[(size_t)c * C_ + h * DH_ + l];
        }
        pacc[part][l] = a;
    }
    __syncthreads();
    if (part == 0) {
        float acc = pacc[0][l];
#pragma unroll
        for (int p = 1; p < AGG_PARTS; ++p) acc += pacc[p][l];
        gvn[((size_t)bh * N_ + g) * DH_ + l] = acc;
    }
}

// ---------------------------------------------------------------------------
// K7: out — 1024 blocks, WpT coalesced (r9 state, known-good)
// ---------------------------------------------------------------------------
__global__ __launch_bounds__(384) void out_kernel(const float* __restrict__ gvn,
                                                  const float* __restrict__ wpT,
                                                  const float* __restrict__ bp,
                                                  float* __restrict__ out) {
    __shared__ float vals[C_];
    int bn = blockIdx.x;                  // 0..1023
    int b = bn >> 6, n = bn & 63;
    int t = threadIdx.x;
    int h = t >> 6, d = t & 63;
    vals[t] = gvn[((size_t)(b * H_ + h) * N_ + n) * DH_ + d];
    __syncthreads();
    float s = bp[t];
#pragma unroll 8
    for (int c = 0; c < C_; ++c)
        s += vals[c] * wpT[(size_t)c * C_ + t];
    out[(size_t)bn * C_ + t] = s;
}

// ---------------------------------------------------------------------------
extern "C" void kernel_launch(void* const* d_in, const int* in_sizes, int n_in,
                              void* d_out, int out_size, void* d_ws, size_t ws_size,
                              hipStream_t stream) {
    (void)in_sizes; (void)n_in; (void)out_size; (void)ws_size;
    const float* query = (const float*)d_in[0];
    const float* key   = (const float*)d_in[1];
    const float* Wq    = (const float*)d_in[2];
    const float* Wk    = (const float*)d_in[3];
    const float* Wv    = (const float*)d_in[4];
    const float* Wp    = (const float*)d_in[5];
    const float* bp    = (const float*)d_in[6];
    float* out = (float*)d_out;

    char* ws = (char*)d_ws;
    size_t off = 0;
    unsigned short* khi  = (unsigned short*)(ws + off); off += (size_t)B_ * S_ * C_ * 2;
    unsigned short* klo  = (unsigned short*)(ws + off); off += (size_t)B_ * S_ * C_ * 2;
    float* qk            = (float*)(ws + off);          off += (size_t)B_ * H_ * N_ * C_ * 4;
    unsigned short* qkhi = (unsigned short*)(ws + off); off += (size_t)B_ * H_ * N_ * C_ * 2;
    unsigned short* qklo = (unsigned short*)(ws + off); off += (size_t)B_ * H_ * N_ * C_ * 2;
    unsigned int* idx    = (unsigned int*)(ws + off);   off += (size_t)B_ * H_ * S_ * 4;
    unsigned int* order  = (unsigned int*)(ws + off);   off += (size_t)B_ * H_ * S_ * 4;
    unsigned int* offs   = (unsigned int*)(ws + off);   off += (size_t)B_ * H_ * 65 * 4;
    float* gvn           = (float*)(ws + off);          off += (size_t)B_ * H_ * N_ * DH_ * 4;
    float* wpT           = (float*)(ws + off);          off += (size_t)C_ * C_ * 4;
    float* wvT           = (float*)(ws + off);          off += (size_t)C_ * C_ * 4;
    unsigned int* fcnt   = (unsigned int*)(ws + off);   off += 256;
    unsigned int* flist  = (unsigned int*)(ws + off);   off += (size_t)LISTCAP * 4;

    hipMemsetAsync(fcnt, 0, 256, stream);

    prepqk_kernel<<<PREP_BLOCKS + QK_BLOCKS + TR_BLOCKS, 384, 0, stream>>>(
        key, khi, klo, query, Wq, Wk, qk, qkhi, qklo, Wp, Wv, wpT, wvT);
    attn_kernel<<<dim3(S_ / 128, H_, B_), 256, 0, stream>>>(qkhi, qklo, khi, klo, idx, fcnt, flist);
    fixup_kernel<<<256, 256, 0, stream>>>(qk, key, flist, fcnt, idx);
    hist_build_kernel<<<B_ * H_, 256, 0, stream>>>(idx, offs, order);
    aggv_kernel<<<dim3(N_, H_, B_), 512, 0, stream>>>(khi, order, offs, wvT, gvn);
    out_kernel<<<B_ * N_, 384, 0, stream>>>(gvn, wpT, bp, out);
}